// Round 10
// baseline (158.450 us; speedup 1.0000x reference)
//
#include <hip/hip_runtime.h>

// AnomalyAttention forward, MI355X gfx950.
// B=8, N=1024, D=1024. Out = [Z (8*1024*1024 f32), P (8*1024*1024 f32)].
// Round 10: g256_body sync restructure — counted waits, 3 barriers/K-tile
// (was 8). Reads issued early (all-B + A0 in ph1, A1 in ph2); compiler's
// precise lgkmcnt lets MFMA overlap other waves' ds_reads. Barrier ledger:
//   B#1 after MFMA A0xB1: all waves' B reads used/returned -> stage B(t+2)
//   B#2 after MFMA A1xB1: all waves' A reads used/returned -> stage A(t+2)
//   B#3 after vmcnt(8):   tile t+1's 8 loads landed -> publish
// Graph identical to round 9 (133 us): prep_g / xq(gemm3b) / sc_vt /
// softmax / sv_prior.

typedef __attribute__((ext_vector_type(8))) short bf16x8;
typedef __attribute__((ext_vector_type(4))) float f32x4;
typedef unsigned short ushort_t;

#define DI __device__ __forceinline__

constexpr long NN = 1024L * 1024L;
constexpr long ND = 1024L * 1024L;

DI ushort_t f2bf(float f) {  // round-to-nearest-even f32 -> bf16 bits
    unsigned int u = __float_as_uint(f);
    u = u + 0x7fffu + ((u >> 16) & 1u);
    return (ushort_t)(u >> 16);
}

// ---------------------------------------------------------------------------
// 128x256 pipelined GEMM body (verified round-3/6): 3 LDS buffers, XOR
// swizzle, 2 phases/K-tile, prefetch distance 2, vmcnt(6). UNCHANGED.
// ---------------------------------------------------------------------------
template <int OUT_BF16>
DI void g3b_body(const ushort_t* __restrict__ Ab, const ushort_t* __restrict__ Bb,
                 void* __restrict__ Cb, int ldA, int ldB, int ldC,
                 float scale, int bx, int by, ushort_t* lds)
{
    constexpr int BUF   = 24576;
    constexpr int B_OFF = 8192;

    const int tid  = threadIdx.x;
    const int wave = tid >> 6;
    const int lane = tid & 63;
    const int wm   = wave >> 2;
    const int wn   = wave & 3;
    const int gm   = bx * 128;
    const int gn   = by * 256;

    const int srow = tid >> 3;
    const int scol = 8 * ((tid & 7) ^ (srow & 7));
    const int sdst = wave * 512;

    auto stageA = [&](int t, int d, int h) {
        const ushort_t* src = Ab + (long)(gm + h * 64 + srow) * ldA + t * 64 + scol;
        __builtin_amdgcn_global_load_lds(
            (const __attribute__((address_space(1))) void*)src,
            (__attribute__((address_space(3))) void*)(&lds[d * BUF + h * 4096 + sdst]),
            16, 0, 0);
    };
    auto stageB = [&](int t, int d, int h, int j) {
        const ushort_t* src = Bb + (long)(gn + h * 128 + j * 64 + srow) * ldB + t * 64 + scol;
        __builtin_amdgcn_global_load_lds(
            (const __attribute__((address_space(1))) void*)src,
            (__attribute__((address_space(3))) void*)(&lds[d * BUF + B_OFF + h * 8192 + j * 4096 + sdst]),
            16, 0, 0);
    };

    const int arow = wm * 64 + (lane & 15);
    const int brow = wn * 64 + (lane & 15);
    const int cs0 = (((lane >> 4) * 16) ^ ((lane & 7) << 4)) >> 1;
    const int cs1 = ((64 + (lane >> 4) * 16) ^ ((lane & 7) << 4)) >> 1;

    f32x4 acc[4][4];
#pragma unroll
    for (int m = 0; m < 4; ++m)
#pragma unroll
        for (int n = 0; n < 4; ++n) acc[m][n] = (f32x4){0.f, 0.f, 0.f, 0.f};

    stageA(0, 0, 0); stageA(0, 0, 1);
    stageB(0, 0, 0, 0); stageB(0, 0, 0, 1); stageB(0, 0, 1, 0); stageB(0, 0, 1, 1);
    stageA(1, 1, 0); stageA(1, 1, 1);
    stageB(1, 1, 0, 0); stageB(1, 1, 0, 1); stageB(1, 1, 1, 0); stageB(1, 1, 1, 1);
    asm volatile("s_waitcnt vmcnt(6)" ::: "memory");
    __builtin_amdgcn_s_barrier();
    __builtin_amdgcn_sched_barrier(0);

    int cur = 0;
    for (int t = 0; t < 16; ++t) {
        const int nxt = (cur == 0) ? 2 : cur - 1;
        const ushort_t* la = &lds[cur * BUF];
        const ushort_t* lb = &lds[cur * BUF + B_OFF];

        bf16x8 a[2][4], b[2][4];
#pragma unroll
        for (int mi = 0; mi < 4; ++mi) {
            a[0][mi] = *(const bf16x8*)&la[(arow + mi * 16) * 64 + cs0];
            a[1][mi] = *(const bf16x8*)&la[(arow + mi * 16) * 64 + cs1];
        }
#pragma unroll
        for (int ni = 0; ni < 2; ++ni) {
            b[0][ni] = *(const bf16x8*)&lb[(brow + ni * 16) * 64 + cs0];
            b[1][ni] = *(const bf16x8*)&lb[(brow + ni * 16) * 64 + cs1];
        }
        if (t < 14) {
            stageB(t + 2, nxt, 0, 0); stageB(t + 2, nxt, 0, 1);
            stageB(t + 2, nxt, 1, 0); stageB(t + 2, nxt, 1, 1);
        }
        __builtin_amdgcn_s_barrier();
        asm volatile("s_waitcnt lgkmcnt(0)" ::: "memory");
        __builtin_amdgcn_sched_barrier(0);
        __builtin_amdgcn_s_setprio(1);
#pragma unroll
        for (int mi = 0; mi < 4; ++mi)
#pragma unroll
            for (int ni = 0; ni < 2; ++ni) {
                acc[mi][ni] = __builtin_amdgcn_mfma_f32_16x16x32_bf16(a[0][mi], b[0][ni], acc[mi][ni], 0, 0, 0);
                acc[mi][ni] = __builtin_amdgcn_mfma_f32_16x16x32_bf16(a[1][mi], b[1][ni], acc[mi][ni], 0, 0, 0);
            }
        __builtin_amdgcn_s_setprio(0);
        __builtin_amdgcn_s_barrier();
        __builtin_amdgcn_sched_barrier(0);

#pragma unroll
        for (int ni = 2; ni < 4; ++ni) {
            b[0][ni] = *(const bf16x8*)&lb[(brow + ni * 16) * 64 + cs0];
            b[1][ni] = *(const bf16x8*)&lb[(brow + ni * 16) * 64 + cs1];
        }
        if (t < 14) { stageA(t + 2, nxt, 0); stageA(t + 2, nxt, 1); }
        __builtin_amdgcn_s_barrier();
        asm volatile("s_waitcnt lgkmcnt(0)" ::: "memory");
        if (t < 14) asm volatile("s_waitcnt vmcnt(6)" ::: "memory");
        else        asm volatile("s_waitcnt vmcnt(0)" ::: "memory");
        __builtin_amdgcn_sched_barrier(0);
        __builtin_amdgcn_s_setprio(1);
#pragma unroll
        for (int mi = 0; mi < 4; ++mi)
#pragma unroll
            for (int ni = 2; ni < 4; ++ni) {
                acc[mi][ni] = __builtin_amdgcn_mfma_f32_16x16x32_bf16(a[0][mi], b[0][ni], acc[mi][ni], 0, 0, 0);
                acc[mi][ni] = __builtin_amdgcn_mfma_f32_16x16x32_bf16(a[1][mi], b[1][ni], acc[mi][ni], 0, 0, 0);
            }
        __builtin_amdgcn_s_setprio(0);
        __builtin_amdgcn_s_barrier();
        __builtin_amdgcn_sched_barrier(0);

        cur = (cur == 2) ? 0 : cur + 1;
    }

    if (OUT_BF16) {
        ushort_t* el = lds;
#pragma unroll
        for (int mi = 0; mi < 4; ++mi)
#pragma unroll
            for (int ni = 0; ni < 4; ++ni)
#pragma unroll
                for (int r = 0; r < 4; ++r)
                    el[(wm * 64 + mi * 16 + (lane >> 4) * 4 + r) * 256 +
                       wn * 64 + ni * 16 + (lane & 15)] = f2bf(acc[mi][ni][r] * scale);
        __builtin_amdgcn_s_barrier();
        ushort_t* C = (ushort_t*)Cb;
#pragma unroll
        for (int rr = 0; rr < 8; ++rr) {
            const int row = rr * 16 + (tid >> 5);
            const int col = (tid & 31) * 8;
            *(bf16x8*)&C[(long)(gm + row) * ldC + gn + col] =
                *(const bf16x8*)&el[row * 256 + col];
        }
    } else {
        float* el = (float*)lds;
        float* C  = (float*)Cb;
#pragma unroll
        for (int h = 0; h < 2; ++h) {
            if (wm == h) {
#pragma unroll
                for (int mi = 0; mi < 4; ++mi)
#pragma unroll
                    for (int ni = 0; ni < 4; ++ni)
#pragma unroll
                        for (int r = 0; r < 4; ++r)
                            el[(mi * 16 + (lane >> 4) * 4 + r) * 256 +
                               wn * 64 + ni * 16 + (lane & 15)] = acc[mi][ni][r] * scale;
            }
            __builtin_amdgcn_s_barrier();
#pragma unroll
            for (int i = 0; i < 8; ++i) {
                const int cc  = i * 512 + tid;
                const int row = cc >> 6;
                const int c4  = (cc & 63) * 4;
                *(float4*)&C[(long)(gm + h * 64 + row) * ldC + gn + c4] =
                    *(const float4*)&el[row * 256 + c4];
            }
            __builtin_amdgcn_s_barrier();
        }
    }
}

template <int OUT_BF16>
__global__ __launch_bounds__(512, 2)
void gemm3b(const ushort_t* __restrict__ A, const ushort_t* __restrict__ B,
            void* __restrict__ Cout, int ldA, int ldB, int ldC,
            long sA, long sB, long sC, float scale,
            int n0, int n1, int xfirst)
{
    __shared__ ushort_t lds[3 * 24576];
    const int total = gridDim.x;
    const int lin   = blockIdx.x;
    const int swz   = (lin & 7) * (total >> 3) + (lin >> 3);
    const int c0    = swz % n0;
    const int rem   = swz / n0;
    const int c1    = rem % n1;
    const int bz    = rem / n1;
    const int bx    = xfirst ? c0 : c1;
    const int by    = xfirst ? c1 : c0;
    void* Cb = OUT_BF16 ? (void*)((ushort_t*)Cout + (long)bz * sC)
                        : (void*)((float*)Cout + (long)bz * sC);
    g3b_body<OUT_BF16>(A + (long)bz * sA, B + (long)bz * sB, Cb,
                       ldA, ldB, ldC, scale, bx, by, lds);
}

// ---------------------------------------------------------------------------
// 256x256 GEMM body, round-10 sync restructure: counted waits, 3 barriers
// per K-tile. BK=64, 8 waves 2Mx4N, per-wave 128x64, 2 LDS bufs, vmcnt(8).
// Reads: ph1 issues A0+B0+B1 (16 b128), ph2 issues A1 (8); compiler inserts
// precise per-use lgkmcnt -> MFMA overlaps other waves' reads.
// ---------------------------------------------------------------------------
template <int OUT_BF16>
DI void g256_body(const ushort_t* __restrict__ Ab, const ushort_t* __restrict__ Bb,
                  void* __restrict__ Cb, int ldA, int ldB, int ldC,
                  float scale, int bx, int by, ushort_t* ldsp)
{
    constexpr int BUF   = 32768;
    constexpr int B_OFF = 16384;

    const int tid  = threadIdx.x;
    const int wave = tid >> 6;
    const int lane = tid & 63;
    const int wm   = wave >> 2;
    const int wn   = wave & 3;
    const int gm   = bx * 256;
    const int gn   = by * 256;

    const int srow = tid >> 3;
    const int scol = 8 * ((tid & 7) ^ (srow & 7));
    const int sdst = wave * 512;

    auto stage = [&](int t, int d, int op, int h) {
        const ushort_t* g  = op ? Bb : Ab;
        const int       ld = op ? ldB : ldA;
        const int       g0 = (op ? gn : gm) + h * 128;
#pragma unroll
        for (int j = 0; j < 2; ++j) {
            const ushort_t* src = g + (long)(g0 + j * 64 + srow) * ld + t * 64 + scol;
            __builtin_amdgcn_global_load_lds(
                (const __attribute__((address_space(1))) void*)src,
                (__attribute__((address_space(3))) void*)
                    (&ldsp[d * BUF + op * B_OFF + h * 8192 + j * 4096 + sdst]),
                16, 0, 0);
        }
    };

    const int arow = wm * 128 + (lane & 15);
    const int brow = wn * 64 + (lane & 15);
    const int cs0 = (((lane >> 4) * 16) ^ ((lane & 7) << 4)) >> 1;
    const int cs1 = ((64 + (lane >> 4) * 16) ^ ((lane & 7) << 4)) >> 1;

    f32x4 acc[8][4];
#pragma unroll
    for (int m = 0; m < 8; ++m)
#pragma unroll
        for (int n = 0; n < 4; ++n) acc[m][n] = (f32x4){0.f, 0.f, 0.f, 0.f};

    stage(0, 0, 0, 0); stage(0, 0, 0, 1); stage(0, 0, 1, 0); stage(0, 0, 1, 1);
    stage(1, 1, 0, 0); stage(1, 1, 0, 1); stage(1, 1, 1, 0); stage(1, 1, 1, 1);
    asm volatile("s_waitcnt vmcnt(8)" ::: "memory");
    __builtin_amdgcn_s_barrier();
    __builtin_amdgcn_sched_barrier(0);

#pragma unroll 2
    for (int t = 0; t < 16; ++t) {
        const int cur = t & 1;
        const ushort_t* la = &ldsp[cur * BUF];
        const ushort_t* lb = &ldsp[cur * BUF + B_OFF];

        bf16x8 a0[2][4], a1[2][4], b0[2][2], b1[2][2];
        // ---- ph1: issue A0 + B0 + B1 reads; MFMA A0 x B0 ----
#pragma unroll
        for (int mi = 0; mi < 4; ++mi) {
            a0[0][mi] = *(const bf16x8*)&la[(arow + mi * 16) * 64 + cs0];
            a0[1][mi] = *(const bf16x8*)&la[(arow + mi * 16) * 64 + cs1];
        }
#pragma unroll
        for (int ni = 0; ni < 2; ++ni) {
            b0[0][ni] = *(const bf16x8*)&lb[(brow + ni * 16) * 64 + cs0];
            b0[1][ni] = *(const bf16x8*)&lb[(brow + ni * 16) * 64 + cs1];
            b1[0][ni] = *(const bf16x8*)&lb[(brow + (ni + 2) * 16) * 64 + cs0];
            b1[1][ni] = *(const bf16x8*)&lb[(brow + (ni + 2) * 16) * 64 + cs1];
        }
        __builtin_amdgcn_s_setprio(1);
#pragma unroll
        for (int mi = 0; mi < 4; ++mi)
#pragma unroll
            for (int ni = 0; ni < 2; ++ni) {
                acc[mi][ni] = __builtin_amdgcn_mfma_f32_16x16x32_bf16(a0[0][mi], b0[0][ni], acc[mi][ni], 0, 0, 0);
                acc[mi][ni] = __builtin_amdgcn_mfma_f32_16x16x32_bf16(a0[1][mi], b0[1][ni], acc[mi][ni], 0, 0, 0);
            }
        __builtin_amdgcn_s_setprio(0);

        // ---- ph2: issue A1 reads; MFMA A0 x B1 ----
#pragma unroll
        for (int mi = 0; mi < 4; ++mi) {
            a1[0][mi] = *(const bf16x8*)&la[(arow + (mi + 4) * 16) * 64 + cs0];
            a1[1][mi] = *(const bf16x8*)&la[(arow + (mi + 4) * 16) * 64 + cs1];
        }
        __builtin_amdgcn_s_setprio(1);
#pragma unroll
        for (int mi = 0; mi < 4; ++mi)
#pragma unroll
            for (int ni = 0; ni < 2; ++ni) {
                acc[mi][ni + 2] = __builtin_amdgcn_mfma_f32_16x16x32_bf16(a0[0][mi], b1[0][ni], acc[mi][ni + 2], 0, 0, 0);
                acc[mi][ni + 2] = __builtin_amdgcn_mfma_f32_16x16x32_bf16(a0[1][mi], b1[1][ni], acc[mi][ni + 2], 0, 0, 0);
            }
        __builtin_amdgcn_s_setprio(0);

        // B#1: every wave's B0/B1 reads were used above -> returned.
        __builtin_amdgcn_sched_barrier(0);
        __builtin_amdgcn_s_barrier();
        __builtin_amdgcn_sched_barrier(0);
        if (t < 14) { stage(t + 2, cur, 1, 0); stage(t + 2, cur, 1, 1); }

        // ---- ph3: MFMA A1 x B1 ----
        __builtin_amdgcn_s_setprio(1);
#pragma unroll
        for (int mi = 0; mi < 4; ++mi)
#pragma unroll
            for (int ni = 0; ni < 2; ++ni) {
                acc[mi + 4][ni + 2] = __builtin_amdgcn_mfma_f32_16x16x32_bf16(a1[0][mi], b1[0][ni], acc[mi + 4][ni + 2], 0, 0, 0);
                acc[mi + 4][ni + 2] = __builtin_amdgcn_mfma_f32_16x16x32_bf16(a1[1][mi], b1[1][ni], acc[mi + 4][ni + 2], 0, 0, 0);
            }
        __builtin_amdgcn_s_setprio(0);

        // B#2: every wave's A0/A1 reads were used above -> returned.
        __builtin_amdgcn_sched_barrier(0);
        __builtin_amdgcn_s_barrier();
        __builtin_amdgcn_sched_barrier(0);
        if (t < 14) { stage(t + 2, cur, 0, 0); stage(t + 2, cur, 0, 1); }

        // ---- ph4: MFMA A1 x B0; wait tile t+1; publish ----
        __builtin_amdgcn_s_setprio(1);
#pragma unroll
        for (int mi = 0; mi < 4; ++mi)
#pragma unroll
            for (int ni = 0; ni < 2; ++ni) {
                acc[mi + 4][ni] = __builtin_amdgcn_mfma_f32_16x16x32_bf16(a1[0][mi], b0[0][ni], acc[mi + 4][ni], 0, 0, 0);
                acc[mi + 4][ni] = __builtin_amdgcn_mfma_f32_16x16x32_bf16(a1[1][mi], b0[1][ni], acc[mi + 4][ni], 0, 0, 0);
            }
        __builtin_amdgcn_s_setprio(0);
        if (t < 14)       asm volatile("s_waitcnt vmcnt(8)" ::: "memory");
        else if (t == 14) asm volatile("s_waitcnt vmcnt(0)" ::: "memory");
        __builtin_amdgcn_sched_barrier(0);
        __builtin_amdgcn_s_barrier();   // B#3: publish tile t+1
        __builtin_amdgcn_sched_barrier(0);
    }

    if (OUT_BF16) {
        ushort_t* el = ldsp;
#pragma unroll
        for (int mi = 0; mi < 8; ++mi)
#pragma unroll
            for (int ni = 0; ni < 4; ++ni)
#pragma unroll
                for (int r = 0; r < 4; ++r)
                    el[(wm * 128 + mi * 16 + (lane >> 4) * 4 + r) * 256 +
                       wn * 64 + ni * 16 + (lane & 15)] = f2bf(acc[mi][ni][r] * scale);
        __builtin_amdgcn_s_barrier();
        ushort_t* C = (ushort_t*)Cb;
#pragma unroll
        for (int i = 0; i < 16; ++i) {
            const int cc  = i * 512 + tid;
            const int row = cc >> 5;
            const int col = (cc & 31) * 8;
            *(bf16x8*)&C[(long)(gm + row) * ldC + gn + col] =
                *(const bf16x8*)&el[row * 256 + col];
        }
    } else {
        float* el = (float*)ldsp;
        float* C  = (float*)Cb;
#pragma unroll
        for (int h = 0; h < 2; ++h) {
            if (wm == h) {
#pragma unroll
                for (int mi = 0; mi < 8; ++mi)
#pragma unroll
                    for (int ni = 0; ni < 4; ++ni)
#pragma unroll
                        for (int r = 0; r < 4; ++r)
                            el[(mi * 16 + (lane >> 4) * 4 + r) * 256 +
                               wn * 64 + ni * 16 + (lane & 15)] = acc[mi][ni][r] * scale;
            }
            __builtin_amdgcn_s_barrier();
#pragma unroll
            for (int i = 0; i < 16; ++i) {
                const int cc  = i * 512 + tid;
                const int row = cc >> 6;
                const int c4  = (cc & 63) * 4;
                *(float4*)&C[(long)(gm + h * 128 + row) * ldC + gn + c4] =
                    *(const float4*)&el[row * 256 + c4];
            }
            __builtin_amdgcn_s_barrier();
        }
    }
}

// ---------------------------------------------------------------------------
// prep_g: 256 blocks x 512 thr (1 block/CU), ~20.5 KB LDS. UNCHANGED.
//   blocks 0..159:  x -> bf16 + sigma + prior rowsum
//   blocks 160..191: WvT transpose, 8 tiles each
//   blocks 192..255: G = Wk * Wq^T, 2-deep reg-prefetch pipeline
// ---------------------------------------------------------------------------
__global__ __launch_bounds__(512)
void prep_g(const float* __restrict__ x, const float* __restrict__ Ws,
            const float* __restrict__ Wq, const float* __restrict__ Wk,
            const float* __restrict__ Wv,
            ushort_t* __restrict__ xh, float* __restrict__ sigma,
            float* __restrict__ rowsum,
            ushort_t* __restrict__ WvT, ushort_t* __restrict__ G)
{
    __shared__ char smem[20608];
    const int blk = blockIdx.x;
    const int tid = threadIdx.x;

    if (blk < 160) {
        const int wave = tid >> 6, lane = tid & 63;
        for (int row = blk * 8 + wave; row < 8192; row += 1280) {
            const float* xr = x + (long)row * 1024;
            float dot = 0.f;
#pragma unroll
            for (int c = 0; c < 4; ++c) {
                const int i = c * 256 + lane * 4;
                float4 v = *(const float4*)(xr + i);
                float4 w = *(const float4*)(Ws + i);
                dot += v.x * w.x + v.y * w.y + v.z * w.z + v.w * w.w;
                ushort4 o;
                o.x = f2bf(v.x); o.y = f2bf(v.y); o.z = f2bf(v.z); o.w = f2bf(v.w);
                *(ushort4*)(xh + (long)row * 1024 + i) = o;
            }
#pragma unroll
            for (int o = 32; o; o >>= 1) dot += __shfl_down(dot, o);
            float sg;
            if (lane == 0) {
                float s = 1.f / (1.f + __expf(-5.f * dot)) + 1e-5f;
                sg = exp2f(s * 1.5849625007211562f) - 1.f;   // 3^s - 1
            }
            sg = __shfl(sg, 0);
            const int i = row & 1023;
            const float c = -0.5f / (sg * sg);
            float a = 0.f;
            for (int j = lane; j < 1024; j += 64) {
                float d = (float)(i - j);
                a += __expf(c * d * d);
            }
#pragma unroll
            for (int o = 32; o; o >>= 1) a += __shfl_down(a, o);
            if (lane == 0) {
                sigma[row]  = sg;
                rowsum[row] = (0.3989422804014327f / sg) * a;
            }
        }
    } else if (blk < 192) {
        float (*s)[65] = (float(*)[65])smem;
        const int r = tid >> 4, c4 = (tid & 15) * 4;
#pragma unroll
        for (int it = 0; it < 8; ++it) {
            const int tile = (blk - 160) * 8 + it;
            const int tr = (tile >> 4) * 64, tc = (tile & 15) * 64;
#pragma unroll
            for (int rr = r; rr < 64; rr += 32) {
                float4 v = *(const float4*)(Wv + (long)(tr + rr) * 1024 + tc + c4);
                s[rr][c4] = v.x; s[rr][c4 + 1] = v.y; s[rr][c4 + 2] = v.z; s[rr][c4 + 3] = v.w;
            }
            __syncthreads();
#pragma unroll
            for (int rr = r; rr < 64; rr += 32) {
                ushort4 o;
                o.x = f2bf(s[c4][rr]);     o.y = f2bf(s[c4 + 1][rr]);
                o.z = f2bf(s[c4 + 2][rr]); o.w = f2bf(s[c4 + 3][rr]);
                *(ushort4*)(WvT + (long)(tc + rr) * 1024 + tr + c4) = o;
            }
            __syncthreads();
        }
    } else {
        ushort_t* sA = (ushort_t*)smem;
        ushort_t* sB = sA + 5120;
        const int g  = blk - 192;
        const int gm = (g >> 3) * 128, gn = (g & 7) * 128;
        const int wave = tid >> 6, lane = tid & 63;
        const int wm = wave >> 2, wn = wave & 3;
        const int lrow = tid >> 3, lcol = (tid & 7) * 4;
        const float* A0 = Wk + (long)(gm + lrow) * 1024 + lcol;
        const float* A1 = Wk + (long)(gm + 64 + lrow) * 1024 + lcol;
        const float* B0 = Wq + (long)(gn + lrow) * 1024 + lcol;
        const float* B1 = Wq + (long)(gn + 64 + lrow) * 1024 + lcol;

        f32x4 acc[4][2];
#pragma unroll
        for (int m = 0; m < 4; ++m)
#pragma unroll
            for (int n = 0; n < 2; ++n) acc[m][n] = (f32x4){0.f, 0.f, 0.f, 0.f};

        auto wr = [&](float4 a0, float4 a1, float4 b0, float4 b1) {
            ushort4 o;
            o.x = f2bf(a0.x); o.y = f2bf(a0.y); o.z = f2bf(a0.z); o.w = f2bf(a0.w);
            *(ushort4*)&sA[lrow * 40 + lcol] = o;
            o.x = f2bf(a1.x); o.y = f2bf(a1.y); o.z = f2bf(a1.z); o.w = f2bf(a1.w);
            *(ushort4*)&sA[(64 + lrow) * 40 + lcol] = o;
            o.x = f2bf(b0.x); o.y = f2bf(b0.y); o.z = f2bf(b0.z); o.w = f2bf(b0.w);
            *(ushort4*)&sB[lrow * 40 + lcol] = o;
            o.x = f2bf(b1.x); o.y = f2bf(b1.y); o.z = f2bf(b1.z); o.w = f2bf(b1.w);
            *(ushort4*)&sB[(64 + lrow) * 40 + lcol] = o;
        };
        auto mm = [&]() {
            bf16x8 af[4], bfv[2];
#pragma unroll
            for (int mi = 0; mi < 4; ++mi)
                af[mi] = *(const bf16x8*)&sA[(wm * 64 + mi * 16 + (lane & 15)) * 40 + (lane >> 4) * 8];
#pragma unroll
            for (int ni = 0; ni < 2; ++ni)
                bfv[ni] = *(const bf16x8*)&sB[(wn * 32 + ni * 16 + (lane & 15)) * 40 + (lane >> 4) * 8];
#pragma unroll
            for (int mi = 0; mi < 4; ++mi)
#pragma unroll
                for (int ni = 0; ni < 2; ++ni)
                    acc[mi][ni] = __builtin_amdgcn_mfma_f32_16x16x32_bf16(af[mi], bfv[ni], acc[mi][ni], 0, 0, 0);
        };

        float4 a0A = *(const float4*)(A0);      float4 a1A = *(const float4*)(A1);
        float4 b0A = *(const float4*)(B0);      float4 b1A = *(const float4*)(B1);
        float4 a0B = *(const float4*)(A0 + 32); float4 a1B = *(const float4*)(A1 + 32);
        float4 b0B = *(const float4*)(B0 + 32); float4 b1B = *(const float4*)(B1 + 32);

        for (int k0 = 0; k0 < 1024; k0 += 64) {
            wr(a0A, a1A, b0A, b1A);
            if (k0 < 960) {
                a0A = *(const float4*)(A0 + k0 + 64); a1A = *(const float4*)(A1 + k0 + 64);
                b0A = *(const float4*)(B0 + k0 + 64); b1A = *(const float4*)(B1 + k0 + 64);
            }
            __syncthreads();
            mm();
            __syncthreads();
            wr(a0B, a1B, b0B, b1B);
            if (k0 < 928) {
                a0B = *(const float4*)(A0 + k0 + 96); a1B = *(const float4*)(A1 + k0 + 96);
                b0B = *(const float4*)(B0 + k0 + 96); b1B = *(const float4*)(B1 + k0 + 96);
            }
            __syncthreads();
            mm();
            __syncthreads();
        }
#pragma unroll
        for (int mi = 0; mi < 4; ++mi)
#pragma unroll
            for (int ni = 0; ni < 2; ++ni)
#pragma unroll
                for (int r = 0; r < 4; ++r)
                    G[(long)(gm + wm * 64 + mi * 16 + (lane >> 4) * 4 + r) * 1024 +
                      gn + wn * 32 + ni * 16 + (lane & 15)] = f2bf(acc[mi][ni][r]);
    }
}

// ---------------------------------------------------------------------------
// sc_vt: 256 blocks x 512 thr, 128 KB LDS (one residency round).
// ---------------------------------------------------------------------------
__global__ __launch_bounds__(512, 2)
void sc_vt(const ushort_t* __restrict__ xqh, const ushort_t* __restrict__ xh,
           float* __restrict__ scores,
           const ushort_t* __restrict__ WvT, ushort_t* __restrict__ VTall)
{
    __shared__ ushort_t lds[2 * 32768];
    const int lin = blockIdx.x;
    if (lin < 128) {
        const int bz = lin & 7;
        const int t  = lin >> 3;
        g256_body<0>(xqh + (long)bz * ND, xh + (long)bz * ND,
                     (void*)(scores + (long)bz * NN),
                     1024, 1024, 1024, 0.03125f, t & 3, t >> 2, lds);
    } else {
        const int l  = lin - 128;
        const int l2 = (l & 7) * 16 + (l >> 3);
        g256_body<1>(WvT, xh, (void*)VTall,
                     1024, 1024, 8192, 1.f, l2 & 3, l2 >> 2, lds);
    }
}

// ---------------------------------------------------------------------------
// sv_prior: 256 blocks x 512 thr, 128 KB LDS (one residency round).
// ---------------------------------------------------------------------------
__global__ __launch_bounds__(512, 2)
void sv_prior(const ushort_t* __restrict__ S, const ushort_t* __restrict__ VTall,
              float* __restrict__ Z, const float* __restrict__ sigma,
              const float* __restrict__ rowsum, float* __restrict__ P)
{
    __shared__ ushort_t lds[2 * 32768];
    const int lin = blockIdx.x;
    const int tid = threadIdx.x;
    if (lin < 128) {
        const int bz = lin & 7;
        const int t  = lin >> 3;
        g256_body<0>(S + (long)bz * NN, VTall + bz * 1024,
                     (void*)(Z + (long)bz * ND),
                     1024, 8192, 1024, 1.f, t & 3, t >> 2, lds);
    } else {
        const int l = lin - 128;
        const int b = l >> 4;
        float* sred = (float*)lds;
        float a = rowsum[b * 1024 + tid] + rowsum[b * 1024 + 512 + tid];
        sred[tid] = a; __syncthreads();
        for (int o = 256; o; o >>= 1) { if (tid < o) sred[tid] += sred[tid + o]; __syncthreads(); }
        const float bs = sred[0];
        const int r0 = (l & 15) * 64;
#pragma unroll
        for (int it = 0; it < 32; ++it) {
            const int e   = it * 512 + tid;
            const int row = r0 + (e >> 8);
            const int j4  = (e & 255) * 4;
            const float sg  = sigma[(b << 10) + row];
            const float c   = -0.5f / (sg * sg);
            const float inv = 0.3989422804014327f / (sg * bs);
            float4 o;
            float d;
            d = (float)(row - j4);       o.x = inv * __expf(c * d * d);
            d = (float)(row - j4 - 1);   o.y = inv * __expf(c * d * d);
            d = (float)(row - j4 - 2);   o.z = inv * __expf(c * d * d);
            d = (float)(row - j4 - 3);   o.w = inv * __expf(c * d * d);
            *(float4*)&P[(long)b * NN + (long)row * 1024 + j4] = o;
        }
    }
}

// softmax over batch dim (8 values, stride NN)
__global__ void softmax_batch(const float* __restrict__ scores, ushort_t* __restrict__ S)
{
    const long idx = (long)blockIdx.x * 256 + threadIdx.x;
    float v[8], m = -1e30f;
#pragma unroll
    for (int b = 0; b < 8; ++b) { v[b] = scores[(long)b * NN + idx]; m = fmaxf(m, v[b]); }
    float sum = 0.f;
#pragma unroll
    for (int b = 0; b < 8; ++b) { v[b] = __expf(v[b] - m); sum += v[b]; }
    const float inv = 1.f / sum;
#pragma unroll
    for (int b = 0; b < 8; ++b) S[(long)b * NN + idx] = f2bf(v[b] * inv);
}

// ---------------------------------------------------------------------------
extern "C" void kernel_launch(void* const* d_in, const int* in_sizes, int n_in,
                              void* d_out, int out_size, void* d_ws, size_t ws_size,
                              hipStream_t stream)
{
    const float* x  = (const float*)d_in[0];
    const float* Wq = (const float*)d_in[1];
    const float* Wk = (const float*)d_in[2];
    const float* Wv = (const float*)d_in[3];
    const float* Ws = (const float*)d_in[4];
    float* Zout = (float*)d_out;
    float* Pout = Zout + 8 * ND;

    char* base = (char*)d_ws;
    size_t off = 0;
    auto alloc = [&](size_t bytes) {
        void* p = base + off;
        off = (off + bytes + 255) & ~(size_t)255;
        return p;
    };
    ushort_t* xh    = (ushort_t*)alloc(8192L * 1024 * 2);
    ushort_t* G     = (ushort_t*)alloc(NN * 2);
    ushort_t* WvT   = (ushort_t*)alloc(NN * 2);
    ushort_t* xqh   = (ushort_t*)alloc(8192L * 1024 * 2);
    ushort_t* VTall = (ushort_t*)alloc(1024L * 8192 * 2);
    float* sigma    = (float*)alloc(8192 * 4);
    float* rowsum   = (float*)alloc(8192 * 4);
    float*    scores = Pout;   // overlays Pout (consumed by softmax first)
    ushort_t* Sh     = xh;     // overlays xh (x dead after sc_vt)

    prep_g<<<256, 512, 0, stream>>>(x, Ws, Wq, Wk, Wv, xh, sigma, rowsum, WvT, G);
    gemm3b<1><<<256, 512, 0, stream>>>(
        xh, G, xqh, 1024, 1024, 1024, 0, 0, 0, 1.f, 4, 64, 0);
    sc_vt<<<256, 512, 0, stream>>>(xqh, xh, scores, WvT, VTall);
    softmax_batch<<<4096, 256, 0, stream>>>(scores, Sh);
    sv_prior<<<256, 512, 0, stream>>>(Sh, VTall, Zout, sigma, rowsum, Pout);
}

// Round 11
// 124.840 us; speedup vs baseline: 1.2692x; 1.2692x over previous
//
#include <hip/hip_runtime.h>

// AnomalyAttention forward, MI355X gfx950.
// B=8, N=1024, D=1024. Out = [Z (8*1024*1024 f32), P (8*1024*1024 f32)].
// Round 11: revert to round-9 bodies (133 us) + packing fix:
//   - scores scratch moved to workspace (frees Pout early)
//   - prior folded into softmax dispatch (both HBM-bound)
//   - SV runs alone as full-chip 256-block gemm3b
// Graph: prep_g / xq(gemm3b) / sc_vt(g256 pair) / softmax_prior / sv(gemm3b)

typedef __attribute__((ext_vector_type(8))) short bf16x8;
typedef __attribute__((ext_vector_type(4))) float f32x4;
typedef unsigned short ushort_t;

#define DI __device__ __forceinline__

constexpr long NN = 1024L * 1024L;
constexpr long ND = 1024L * 1024L;

DI ushort_t f2bf(float f) {  // round-to-nearest-even f32 -> bf16 bits
    unsigned int u = __float_as_uint(f);
    u = u + 0x7fffu + ((u >> 16) & 1u);
    return (ushort_t)(u >> 16);
}

// ---------------------------------------------------------------------------
// 128x256 pipelined GEMM body (verified round-3/6/9): 3 LDS buffers, XOR
// swizzle, 2 phases/K-tile, prefetch distance 2, vmcnt(6). UNCHANGED.
// ---------------------------------------------------------------------------
template <int OUT_BF16>
DI void g3b_body(const ushort_t* __restrict__ Ab, const ushort_t* __restrict__ Bb,
                 void* __restrict__ Cb, int ldA, int ldB, int ldC,
                 float scale, int bx, int by, ushort_t* lds)
{
    constexpr int BUF   = 24576;
    constexpr int B_OFF = 8192;

    const int tid  = threadIdx.x;
    const int wave = tid >> 6;
    const int lane = tid & 63;
    const int wm   = wave >> 2;
    const int wn   = wave & 3;
    const int gm   = bx * 128;
    const int gn   = by * 256;

    const int srow = tid >> 3;
    const int scol = 8 * ((tid & 7) ^ (srow & 7));
    const int sdst = wave * 512;

    auto stageA = [&](int t, int d, int h) {
        const ushort_t* src = Ab + (long)(gm + h * 64 + srow) * ldA + t * 64 + scol;
        __builtin_amdgcn_global_load_lds(
            (const __attribute__((address_space(1))) void*)src,
            (__attribute__((address_space(3))) void*)(&lds[d * BUF + h * 4096 + sdst]),
            16, 0, 0);
    };
    auto stageB = [&](int t, int d, int h, int j) {
        const ushort_t* src = Bb + (long)(gn + h * 128 + j * 64 + srow) * ldB + t * 64 + scol;
        __builtin_amdgcn_global_load_lds(
            (const __attribute__((address_space(1))) void*)src,
            (__attribute__((address_space(3))) void*)(&lds[d * BUF + B_OFF + h * 8192 + j * 4096 + sdst]),
            16, 0, 0);
    };

    const int arow = wm * 64 + (lane & 15);
    const int brow = wn * 64 + (lane & 15);
    const int cs0 = (((lane >> 4) * 16) ^ ((lane & 7) << 4)) >> 1;
    const int cs1 = ((64 + (lane >> 4) * 16) ^ ((lane & 7) << 4)) >> 1;

    f32x4 acc[4][4];
#pragma unroll
    for (int m = 0; m < 4; ++m)
#pragma unroll
        for (int n = 0; n < 4; ++n) acc[m][n] = (f32x4){0.f, 0.f, 0.f, 0.f};

    stageA(0, 0, 0); stageA(0, 0, 1);
    stageB(0, 0, 0, 0); stageB(0, 0, 0, 1); stageB(0, 0, 1, 0); stageB(0, 0, 1, 1);
    stageA(1, 1, 0); stageA(1, 1, 1);
    stageB(1, 1, 0, 0); stageB(1, 1, 0, 1); stageB(1, 1, 1, 0); stageB(1, 1, 1, 1);
    asm volatile("s_waitcnt vmcnt(6)" ::: "memory");
    __builtin_amdgcn_s_barrier();
    __builtin_amdgcn_sched_barrier(0);

    int cur = 0;
    for (int t = 0; t < 16; ++t) {
        const int nxt = (cur == 0) ? 2 : cur - 1;
        const ushort_t* la = &lds[cur * BUF];
        const ushort_t* lb = &lds[cur * BUF + B_OFF];

        bf16x8 a[2][4], b[2][4];
#pragma unroll
        for (int mi = 0; mi < 4; ++mi) {
            a[0][mi] = *(const bf16x8*)&la[(arow + mi * 16) * 64 + cs0];
            a[1][mi] = *(const bf16x8*)&la[(arow + mi * 16) * 64 + cs1];
        }
#pragma unroll
        for (int ni = 0; ni < 2; ++ni) {
            b[0][ni] = *(const bf16x8*)&lb[(brow + ni * 16) * 64 + cs0];
            b[1][ni] = *(const bf16x8*)&lb[(brow + ni * 16) * 64 + cs1];
        }
        if (t < 14) {
            stageB(t + 2, nxt, 0, 0); stageB(t + 2, nxt, 0, 1);
            stageB(t + 2, nxt, 1, 0); stageB(t + 2, nxt, 1, 1);
        }
        __builtin_amdgcn_s_barrier();
        asm volatile("s_waitcnt lgkmcnt(0)" ::: "memory");
        __builtin_amdgcn_sched_barrier(0);
        __builtin_amdgcn_s_setprio(1);
#pragma unroll
        for (int mi = 0; mi < 4; ++mi)
#pragma unroll
            for (int ni = 0; ni < 2; ++ni) {
                acc[mi][ni] = __builtin_amdgcn_mfma_f32_16x16x32_bf16(a[0][mi], b[0][ni], acc[mi][ni], 0, 0, 0);
                acc[mi][ni] = __builtin_amdgcn_mfma_f32_16x16x32_bf16(a[1][mi], b[1][ni], acc[mi][ni], 0, 0, 0);
            }
        __builtin_amdgcn_s_setprio(0);
        __builtin_amdgcn_s_barrier();
        __builtin_amdgcn_sched_barrier(0);

#pragma unroll
        for (int ni = 2; ni < 4; ++ni) {
            b[0][ni] = *(const bf16x8*)&lb[(brow + ni * 16) * 64 + cs0];
            b[1][ni] = *(const bf16x8*)&lb[(brow + ni * 16) * 64 + cs1];
        }
        if (t < 14) { stageA(t + 2, nxt, 0); stageA(t + 2, nxt, 1); }
        __builtin_amdgcn_s_barrier();
        asm volatile("s_waitcnt lgkmcnt(0)" ::: "memory");
        if (t < 14) asm volatile("s_waitcnt vmcnt(6)" ::: "memory");
        else        asm volatile("s_waitcnt vmcnt(0)" ::: "memory");
        __builtin_amdgcn_sched_barrier(0);
        __builtin_amdgcn_s_setprio(1);
#pragma unroll
        for (int mi = 0; mi < 4; ++mi)
#pragma unroll
            for (int ni = 2; ni < 4; ++ni) {
                acc[mi][ni] = __builtin_amdgcn_mfma_f32_16x16x32_bf16(a[0][mi], b[0][ni], acc[mi][ni], 0, 0, 0);
                acc[mi][ni] = __builtin_amdgcn_mfma_f32_16x16x32_bf16(a[1][mi], b[1][ni], acc[mi][ni], 0, 0, 0);
            }
        __builtin_amdgcn_s_setprio(0);
        __builtin_amdgcn_s_barrier();
        __builtin_amdgcn_sched_barrier(0);

        cur = (cur == 2) ? 0 : cur + 1;
    }

    if (OUT_BF16) {
        ushort_t* el = lds;
#pragma unroll
        for (int mi = 0; mi < 4; ++mi)
#pragma unroll
            for (int ni = 0; ni < 4; ++ni)
#pragma unroll
                for (int r = 0; r < 4; ++r)
                    el[(wm * 64 + mi * 16 + (lane >> 4) * 4 + r) * 256 +
                       wn * 64 + ni * 16 + (lane & 15)] = f2bf(acc[mi][ni][r] * scale);
        __builtin_amdgcn_s_barrier();
        ushort_t* C = (ushort_t*)Cb;
#pragma unroll
        for (int rr = 0; rr < 8; ++rr) {
            const int row = rr * 16 + (tid >> 5);
            const int col = (tid & 31) * 8;
            *(bf16x8*)&C[(long)(gm + row) * ldC + gn + col] =
                *(const bf16x8*)&el[row * 256 + col];
        }
    } else {
        float* el = (float*)lds;
        float* C  = (float*)Cb;
#pragma unroll
        for (int h = 0; h < 2; ++h) {
            if (wm == h) {
#pragma unroll
                for (int mi = 0; mi < 4; ++mi)
#pragma unroll
                    for (int ni = 0; ni < 4; ++ni)
#pragma unroll
                        for (int r = 0; r < 4; ++r)
                            el[(mi * 16 + (lane >> 4) * 4 + r) * 256 +
                               wn * 64 + ni * 16 + (lane & 15)] = acc[mi][ni][r] * scale;
            }
            __builtin_amdgcn_s_barrier();
#pragma unroll
            for (int i = 0; i < 8; ++i) {
                const int cc  = i * 512 + tid;
                const int row = cc >> 6;
                const int c4  = (cc & 63) * 4;
                *(float4*)&C[(long)(gm + h * 64 + row) * ldC + gn + c4] =
                    *(const float4*)&el[row * 256 + c4];
            }
            __builtin_amdgcn_s_barrier();
        }
    }
}

template <int OUT_BF16>
__global__ __launch_bounds__(512, 2)
void gemm3b(const ushort_t* __restrict__ A, const ushort_t* __restrict__ B,
            void* __restrict__ Cout, int ldA, int ldB, int ldC,
            long sA, long sB, long sC, float scale,
            int n0, int n1, int xfirst)
{
    __shared__ ushort_t lds[3 * 24576];
    const int total = gridDim.x;
    const int lin   = blockIdx.x;
    const int swz   = (lin & 7) * (total >> 3) + (lin >> 3);
    const int c0    = swz % n0;
    const int rem   = swz / n0;
    const int c1    = rem % n1;
    const int bz    = rem / n1;
    const int bx    = xfirst ? c0 : c1;
    const int by    = xfirst ? c1 : c0;
    void* Cb = OUT_BF16 ? (void*)((ushort_t*)Cout + (long)bz * sC)
                        : (void*)((float*)Cout + (long)bz * sC);
    g3b_body<OUT_BF16>(A + (long)bz * sA, B + (long)bz * sB, Cb,
                       ldA, ldB, ldC, scale, bx, by, lds);
}

// ---------------------------------------------------------------------------
// 256x256 8-phase GEMM body (verified round-4/9): BK=64, 8 waves 2Mx4N,
// per-wave 128x64, 2 LDS bufs, counted vmcnt(8). UNCHANGED (round-9 form).
// ---------------------------------------------------------------------------
template <int OUT_BF16>
DI void g256_body(const ushort_t* __restrict__ Ab, const ushort_t* __restrict__ Bb,
                  void* __restrict__ Cb, int ldA, int ldB, int ldC,
                  float scale, int bx, int by, ushort_t* ldsp)
{
    constexpr int BUF   = 32768;
    constexpr int B_OFF = 16384;

    const int tid  = threadIdx.x;
    const int wave = tid >> 6;
    const int lane = tid & 63;
    const int wm   = wave >> 2;
    const int wn   = wave & 3;
    const int gm   = bx * 256;
    const int gn   = by * 256;

    const int srow = tid >> 3;
    const int scol = 8 * ((tid & 7) ^ (srow & 7));
    const int sdst = wave * 512;

    auto stage = [&](int t, int d, int op, int h) {
        const ushort_t* g  = op ? Bb : Ab;
        const int       ld = op ? ldB : ldA;
        const int       g0 = (op ? gn : gm) + h * 128;
#pragma unroll
        for (int j = 0; j < 2; ++j) {
            const ushort_t* src = g + (long)(g0 + j * 64 + srow) * ld + t * 64 + scol;
            __builtin_amdgcn_global_load_lds(
                (const __attribute__((address_space(1))) void*)src,
                (__attribute__((address_space(3))) void*)
                    (&ldsp[d * BUF + op * B_OFF + h * 8192 + j * 4096 + sdst]),
                16, 0, 0);
        }
    };

    const int arow = wm * 128 + (lane & 15);
    const int brow = wn * 64 + (lane & 15);
    const int cs0 = (((lane >> 4) * 16) ^ ((lane & 7) << 4)) >> 1;
    const int cs1 = ((64 + (lane >> 4) * 16) ^ ((lane & 7) << 4)) >> 1;

    f32x4 acc[8][4];
#pragma unroll
    for (int m = 0; m < 8; ++m)
#pragma unroll
        for (int n = 0; n < 4; ++n) acc[m][n] = (f32x4){0.f, 0.f, 0.f, 0.f};

    stage(0, 0, 0, 0); stage(0, 0, 0, 1); stage(0, 0, 1, 0); stage(0, 0, 1, 1);
    stage(1, 1, 0, 0); stage(1, 1, 0, 1); stage(1, 1, 1, 0); stage(1, 1, 1, 1);
    asm volatile("s_waitcnt vmcnt(8)" ::: "memory");
    __builtin_amdgcn_s_barrier();
    __builtin_amdgcn_sched_barrier(0);

    bf16x8 a[2][4], b0[2][2], b1[2][2];
#pragma unroll 2
    for (int t = 0; t < 16; ++t) {
        const int cur = t & 1;
        const ushort_t* la = &ldsp[cur * BUF];
        const ushort_t* lb = &ldsp[cur * BUF + B_OFF];

        // ph1
#pragma unroll
        for (int mi = 0; mi < 4; ++mi) {
            a[0][mi] = *(const bf16x8*)&la[(arow + mi * 16) * 64 + cs0];
            a[1][mi] = *(const bf16x8*)&la[(arow + mi * 16) * 64 + cs1];
        }
#pragma unroll
        for (int ni = 0; ni < 2; ++ni) {
            b0[0][ni] = *(const bf16x8*)&lb[(brow + ni * 16) * 64 + cs0];
            b0[1][ni] = *(const bf16x8*)&lb[(brow + ni * 16) * 64 + cs1];
        }
        __builtin_amdgcn_s_barrier();
        asm volatile("s_waitcnt lgkmcnt(0)" ::: "memory");
        __builtin_amdgcn_sched_barrier(0);
        __builtin_amdgcn_s_setprio(1);
#pragma unroll
        for (int mi = 0; mi < 4; ++mi)
#pragma unroll
            for (int ni = 0; ni < 2; ++ni) {
                acc[mi][ni] = __builtin_amdgcn_mfma_f32_16x16x32_bf16(a[0][mi], b0[0][ni], acc[mi][ni], 0, 0, 0);
                acc[mi][ni] = __builtin_amdgcn_mfma_f32_16x16x32_bf16(a[1][mi], b0[1][ni], acc[mi][ni], 0, 0, 0);
            }
        __builtin_amdgcn_s_setprio(0);
        __builtin_amdgcn_s_barrier();
        __builtin_amdgcn_sched_barrier(0);

        // ph2
#pragma unroll
        for (int ni = 0; ni < 2; ++ni) {
            b1[0][ni] = *(const bf16x8*)&lb[(brow + (ni + 2) * 16) * 64 + cs0];
            b1[1][ni] = *(const bf16x8*)&lb[(brow + (ni + 2) * 16) * 64 + cs1];
        }
        __builtin_amdgcn_s_barrier();
        asm volatile("s_waitcnt lgkmcnt(0)" ::: "memory");
        __builtin_amdgcn_sched_barrier(0);
        __builtin_amdgcn_s_setprio(1);
#pragma unroll
        for (int mi = 0; mi < 4; ++mi)
#pragma unroll
            for (int ni = 0; ni < 2; ++ni) {
                acc[mi][ni + 2] = __builtin_amdgcn_mfma_f32_16x16x32_bf16(a[0][mi], b1[0][ni], acc[mi][ni + 2], 0, 0, 0);
                acc[mi][ni + 2] = __builtin_amdgcn_mfma_f32_16x16x32_bf16(a[1][mi], b1[1][ni], acc[mi][ni + 2], 0, 0, 0);
            }
        __builtin_amdgcn_s_setprio(0);
        __builtin_amdgcn_s_barrier();
        __builtin_amdgcn_sched_barrier(0);

        // ph3
#pragma unroll
        for (int mi = 0; mi < 4; ++mi) {
            a[0][mi] = *(const bf16x8*)&la[(arow + (mi + 4) * 16) * 64 + cs0];
            a[1][mi] = *(const bf16x8*)&la[(arow + (mi + 4) * 16) * 64 + cs1];
        }
        if (t < 14) { stage(t + 2, cur, 1, 0); stage(t + 2, cur, 1, 1); }
        __builtin_amdgcn_s_barrier();
        asm volatile("s_waitcnt lgkmcnt(0)" ::: "memory");
        __builtin_amdgcn_sched_barrier(0);
        __builtin_amdgcn_s_setprio(1);
#pragma unroll
        for (int mi = 0; mi < 4; ++mi)
#pragma unroll
            for (int ni = 0; ni < 2; ++ni) {
                acc[mi + 4][ni + 2] = __builtin_amdgcn_mfma_f32_16x16x32_bf16(a[0][mi], b1[0][ni], acc[mi + 4][ni + 2], 0, 0, 0);
                acc[mi + 4][ni + 2] = __builtin_amdgcn_mfma_f32_16x16x32_bf16(a[1][mi], b1[1][ni], acc[mi + 4][ni + 2], 0, 0, 0);
            }
        __builtin_amdgcn_s_setprio(0);
        __builtin_amdgcn_s_barrier();
        __builtin_amdgcn_sched_barrier(0);

        // ph4
        if (t < 14) { stage(t + 2, cur, 0, 0); stage(t + 2, cur, 0, 1); }
        if (t < 14)       asm volatile("s_waitcnt vmcnt(8)" ::: "memory");
        else if (t == 14) asm volatile("s_waitcnt vmcnt(0)" ::: "memory");
        __builtin_amdgcn_sched_barrier(0);
        __builtin_amdgcn_s_setprio(1);
#pragma unroll
        for (int mi = 0; mi < 4; ++mi)
#pragma unroll
            for (int ni = 0; ni < 2; ++ni) {
                acc[mi + 4][ni] = __builtin_amdgcn_mfma_f32_16x16x32_bf16(a[0][mi], b0[0][ni], acc[mi + 4][ni], 0, 0, 0);
                acc[mi + 4][ni] = __builtin_amdgcn_mfma_f32_16x16x32_bf16(a[1][mi], b0[1][ni], acc[mi + 4][ni], 0, 0, 0);
            }
        __builtin_amdgcn_s_setprio(0);
        __builtin_amdgcn_s_barrier();
        __builtin_amdgcn_sched_barrier(0);
    }

    if (OUT_BF16) {
        ushort_t* el = ldsp;
#pragma unroll
        for (int mi = 0; mi < 8; ++mi)
#pragma unroll
            for (int ni = 0; ni < 4; ++ni)
#pragma unroll
                for (int r = 0; r < 4; ++r)
                    el[(wm * 128 + mi * 16 + (lane >> 4) * 4 + r) * 256 +
                       wn * 64 + ni * 16 + (lane & 15)] = f2bf(acc[mi][ni][r] * scale);
        __builtin_amdgcn_s_barrier();
        ushort_t* C = (ushort_t*)Cb;
#pragma unroll
        for (int i = 0; i < 16; ++i) {
            const int cc  = i * 512 + tid;
            const int row = cc >> 5;
            const int col = (cc & 31) * 8;
            *(bf16x8*)&C[(long)(gm + row) * ldC + gn + col] =
                *(const bf16x8*)&el[row * 256 + col];
        }
    } else {
        float* el = (float*)ldsp;
        float* C  = (float*)Cb;
#pragma unroll
        for (int h = 0; h < 2; ++h) {
            if (wm == h) {
#pragma unroll
                for (int mi = 0; mi < 8; ++mi)
#pragma unroll
                    for (int ni = 0; ni < 4; ++ni)
#pragma unroll
                        for (int r = 0; r < 4; ++r)
                            el[(mi * 16 + (lane >> 4) * 4 + r) * 256 +
                               wn * 64 + ni * 16 + (lane & 15)] = acc[mi][ni][r] * scale;
            }
            __builtin_amdgcn_s_barrier();
#pragma unroll
            for (int i = 0; i < 16; ++i) {
                const int cc  = i * 512 + tid;
                const int row = cc >> 6;
                const int c4  = (cc & 63) * 4;
                *(float4*)&C[(long)(gm + h * 128 + row) * ldC + gn + c4] =
                    *(const float4*)&el[row * 256 + c4];
            }
            __builtin_amdgcn_s_barrier();
        }
    }
}

// ---------------------------------------------------------------------------
// prep_g: 256 blocks x 512 thr (1 block/CU), ~20.5 KB LDS. UNCHANGED (r9).
// ---------------------------------------------------------------------------
__global__ __launch_bounds__(512)
void prep_g(const float* __restrict__ x, const float* __restrict__ Ws,
            const float* __restrict__ Wq, const float* __restrict__ Wk,
            const float* __restrict__ Wv,
            ushort_t* __restrict__ xh, float* __restrict__ sigma,
            float* __restrict__ rowsum,
            ushort_t* __restrict__ WvT, ushort_t* __restrict__ G)
{
    __shared__ char smem[20608];
    const int blk = blockIdx.x;
    const int tid = threadIdx.x;

    if (blk < 160) {
        const int wave = tid >> 6, lane = tid & 63;
        for (int row = blk * 8 + wave; row < 8192; row += 1280) {
            const float* xr = x + (long)row * 1024;
            float dot = 0.f;
#pragma unroll
            for (int c = 0; c < 4; ++c) {
                const int i = c * 256 + lane * 4;
                float4 v = *(const float4*)(xr + i);
                float4 w = *(const float4*)(Ws + i);
                dot += v.x * w.x + v.y * w.y + v.z * w.z + v.w * w.w;
                ushort4 o;
                o.x = f2bf(v.x); o.y = f2bf(v.y); o.z = f2bf(v.z); o.w = f2bf(v.w);
                *(ushort4*)(xh + (long)row * 1024 + i) = o;
            }
#pragma unroll
            for (int o = 32; o; o >>= 1) dot += __shfl_down(dot, o);
            float sg;
            if (lane == 0) {
                float s = 1.f / (1.f + __expf(-5.f * dot)) + 1e-5f;
                sg = exp2f(s * 1.5849625007211562f) - 1.f;   // 3^s - 1
            }
            sg = __shfl(sg, 0);
            const int i = row & 1023;
            const float c = -0.5f / (sg * sg);
            float a = 0.f;
            for (int j = lane; j < 1024; j += 64) {
                float d = (float)(i - j);
                a += __expf(c * d * d);
            }
#pragma unroll
            for (int o = 32; o; o >>= 1) a += __shfl_down(a, o);
            if (lane == 0) {
                sigma[row]  = sg;
                rowsum[row] = (0.3989422804014327f / sg) * a;
            }
        }
    } else if (blk < 192) {
        float (*s)[65] = (float(*)[65])smem;
        const int r = tid >> 4, c4 = (tid & 15) * 4;
#pragma unroll
        for (int it = 0; it < 8; ++it) {
            const int tile = (blk - 160) * 8 + it;
            const int tr = (tile >> 4) * 64, tc = (tile & 15) * 64;
#pragma unroll
            for (int rr = r; rr < 64; rr += 32) {
                float4 v = *(const float4*)(Wv + (long)(tr + rr) * 1024 + tc + c4);
                s[rr][c4] = v.x; s[rr][c4 + 1] = v.y; s[rr][c4 + 2] = v.z; s[rr][c4 + 3] = v.w;
            }
            __syncthreads();
#pragma unroll
            for (int rr = r; rr < 64; rr += 32) {
                ushort4 o;
                o.x = f2bf(s[c4][rr]);     o.y = f2bf(s[c4 + 1][rr]);
                o.z = f2bf(s[c4 + 2][rr]); o.w = f2bf(s[c4 + 3][rr]);
                *(ushort4*)(WvT + (long)(tc + rr) * 1024 + tr + c4) = o;
            }
            __syncthreads();
        }
    } else {
        ushort_t* sA = (ushort_t*)smem;
        ushort_t* sB = sA + 5120;
        const int g  = blk - 192;
        const int gm = (g >> 3) * 128, gn = (g & 7) * 128;
        const int wave = tid >> 6, lane = tid & 63;
        const int wm = wave >> 2, wn = wave & 3;
        const int lrow = tid >> 3, lcol = (tid & 7) * 4;
        const float* A0 = Wk + (long)(gm + lrow) * 1024 + lcol;
        const float* A1 = Wk + (long)(gm + 64 + lrow) * 1024 + lcol;
        const float* B0 = Wq + (long)(gn + lrow) * 1024 + lcol;
        const float* B1 = Wq + (long)(gn + 64 + lrow) * 1024 + lcol;

        f32x4 acc[4][2];
#pragma unroll
        for (int m = 0; m < 4; ++m)
#pragma unroll
            for (int n = 0; n < 2; ++n) acc[m][n] = (f32x4){0.f, 0.f, 0.f, 0.f};

        auto wr = [&](float4 a0, float4 a1, float4 b0, float4 b1) {
            ushort4 o;
            o.x = f2bf(a0.x); o.y = f2bf(a0.y); o.z = f2bf(a0.z); o.w = f2bf(a0.w);
            *(ushort4*)&sA[lrow * 40 + lcol] = o;
            o.x = f2bf(a1.x); o.y = f2bf(a1.y); o.z = f2bf(a1.z); o.w = f2bf(a1.w);
            *(ushort4*)&sA[(64 + lrow) * 40 + lcol] = o;
            o.x = f2bf(b0.x); o.y = f2bf(b0.y); o.z = f2bf(b0.z); o.w = f2bf(b0.w);
            *(ushort4*)&sB[lrow * 40 + lcol] = o;
            o.x = f2bf(b1.x); o.y = f2bf(b1.y); o.z = f2bf(b1.z); o.w = f2bf(b1.w);
            *(ushort4*)&sB[(64 + lrow) * 40 + lcol] = o;
        };
        auto mm = [&]() {
            bf16x8 af[4], bfv[2];
#pragma unroll
            for (int mi = 0; mi < 4; ++mi)
                af[mi] = *(const bf16x8*)&sA[(wm * 64 + mi * 16 + (lane & 15)) * 40 + (lane >> 4) * 8];
#pragma unroll
            for (int ni = 0; ni < 2; ++ni)
                bfv[ni] = *(const bf16x8*)&sB[(wn * 32 + ni * 16 + (lane & 15)) * 40 + (lane >> 4) * 8];
#pragma unroll
            for (int mi = 0; mi < 4; ++mi)
#pragma unroll
                for (int ni = 0; ni < 2; ++ni)
                    acc[mi][ni] = __builtin_amdgcn_mfma_f32_16x16x32_bf16(af[mi], bfv[ni], acc[mi][ni], 0, 0, 0);
        };

        float4 a0A = *(const float4*)(A0);      float4 a1A = *(const float4*)(A1);
        float4 b0A = *(const float4*)(B0);      float4 b1A = *(const float4*)(B1);
        float4 a0B = *(const float4*)(A0 + 32); float4 a1B = *(const float4*)(A1 + 32);
        float4 b0B = *(const float4*)(B0 + 32); float4 b1B = *(const float4*)(B1 + 32);

        for (int k0 = 0; k0 < 1024; k0 += 64) {
            wr(a0A, a1A, b0A, b1A);
            if (k0 < 960) {
                a0A = *(const float4*)(A0 + k0 + 64); a1A = *(const float4*)(A1 + k0 + 64);
                b0A = *(const float4*)(B0 + k0 + 64); b1A = *(const float4*)(B1 + k0 + 64);
            }
            __syncthreads();
            mm();
            __syncthreads();
            wr(a0B, a1B, b0B, b1B);
            if (k0 < 928) {
                a0B = *(const float4*)(A0 + k0 + 96); a1B = *(const float4*)(A1 + k0 + 96);
                b0B = *(const float4*)(B0 + k0 + 96); b1B = *(const float4*)(B1 + k0 + 96);
            }
            __syncthreads();
            mm();
            __syncthreads();
        }
#pragma unroll
        for (int mi = 0; mi < 4; ++mi)
#pragma unroll
            for (int ni = 0; ni < 2; ++ni)
#pragma unroll
                for (int r = 0; r < 4; ++r)
                    G[(long)(gm + wm * 64 + mi * 16 + (lane >> 4) * 4 + r) * 1024 +
                      gn + wn * 32 + ni * 16 + (lane & 15)] = f2bf(acc[mi][ni][r]);
    }
}

// ---------------------------------------------------------------------------
// sc_vt: 256 blocks x 512 thr, 128 KB LDS (one residency round). UNCHANGED
// except scores target is a workspace buffer.
// ---------------------------------------------------------------------------
__global__ __launch_bounds__(512, 2)
void sc_vt(const ushort_t* __restrict__ xqh, const ushort_t* __restrict__ xh,
           float* __restrict__ scores,
           const ushort_t* __restrict__ WvT, ushort_t* __restrict__ VTall)
{
    __shared__ ushort_t lds[2 * 32768];
    const int lin = blockIdx.x;
    if (lin < 128) {
        const int bz = lin & 7;
        const int t  = lin >> 3;
        g256_body<0>(xqh + (long)bz * ND, xh + (long)bz * ND,
                     (void*)(scores + (long)bz * NN),
                     1024, 1024, 1024, 0.03125f, t & 3, t >> 2, lds);
    } else {
        const int l  = lin - 128;
        const int l2 = (l & 7) * 16 + (l >> 3);
        g256_body<1>(WvT, xh, (void*)VTall,
                     1024, 1024, 8192, 1.f, l2 & 3, l2 >> 2, lds);
    }
}

// ---------------------------------------------------------------------------
// softmax_prior: 5120 blocks x 256 thr, memory-bound.
//   blocks 0..4095:    batch softmax, scores(ws) -> S (bf16)
//   blocks 4096..5119: prior P -> Pout (each block derives batchsum; 8 rows)
// ---------------------------------------------------------------------------
__global__ __launch_bounds__(256)
void softmax_prior(const float* __restrict__ scores, ushort_t* __restrict__ S,
                   const float* __restrict__ sigma, const float* __restrict__ rowsum,
                   float* __restrict__ P)
{
    __shared__ float sred[256];
    const int blk = blockIdx.x;
    const int tid = threadIdx.x;
    if (blk < 4096) {
        const long idx = (long)blk * 256 + tid;
        float v[8], m = -1e30f;
#pragma unroll
        for (int b = 0; b < 8; ++b) { v[b] = scores[(long)b * NN + idx]; m = fmaxf(m, v[b]); }
        float sum = 0.f;
#pragma unroll
        for (int b = 0; b < 8; ++b) { v[b] = __expf(v[b] - m); sum += v[b]; }
        const float inv = 1.f / sum;
#pragma unroll
        for (int b = 0; b < 8; ++b) S[(long)b * NN + idx] = f2bf(v[b] * inv);
    } else {
        const int l = blk - 4096;          // 0..1023
        const int b = l >> 7;              // 128 blocks per batch
        // batchsum from rowsum (deterministic per-block reduce)
        float a = rowsum[b * 1024 + tid]       + rowsum[b * 1024 + 256 + tid] +
                  rowsum[b * 1024 + 512 + tid] + rowsum[b * 1024 + 768 + tid];
        sred[tid] = a; __syncthreads();
        for (int o = 128; o; o >>= 1) { if (tid < o) sred[tid] += sred[tid + o]; __syncthreads(); }
        const float bs = sred[0];
        const int r0 = (l & 127) * 8;      // 8 rows per block
#pragma unroll
        for (int it = 0; it < 8; ++it) {
            const int e   = it * 256 + tid;        // 0..2047 float4 slots
            const int row = r0 + (e >> 8);
            const int j4  = (e & 255) * 4;
            const float sg  = sigma[(b << 10) + row];
            const float c   = -0.5f / (sg * sg);
            const float inv = 0.3989422804014327f / (sg * bs);
            float4 o;
            float d;
            d = (float)(row - j4);       o.x = inv * __expf(c * d * d);
            d = (float)(row - j4 - 1);   o.y = inv * __expf(c * d * d);
            d = (float)(row - j4 - 2);   o.z = inv * __expf(c * d * d);
            d = (float)(row - j4 - 3);   o.w = inv * __expf(c * d * d);
            *(float4*)&P[(long)b * NN + (long)row * 1024 + j4] = o;
        }
    }
}

// ---------------------------------------------------------------------------
extern "C" void kernel_launch(void* const* d_in, const int* in_sizes, int n_in,
                              void* d_out, int out_size, void* d_ws, size_t ws_size,
                              hipStream_t stream)
{
    const float* x  = (const float*)d_in[0];
    const float* Wq = (const float*)d_in[1];
    const float* Wk = (const float*)d_in[2];
    const float* Wv = (const float*)d_in[3];
    const float* Ws = (const float*)d_in[4];
    float* Zout = (float*)d_out;
    float* Pout = Zout + 8 * ND;

    char* base = (char*)d_ws;
    size_t off = 0;
    auto alloc = [&](size_t bytes) {
        void* p = base + off;
        off = (off + bytes + 255) & ~(size_t)255;
        return p;
    };
    ushort_t* xh     = (ushort_t*)alloc(8192L * 1024 * 2);   // 16.78 MB
    ushort_t* G      = (ushort_t*)alloc(NN * 2);             //  2.10 MB
    ushort_t* WvT    = (ushort_t*)alloc(NN * 2);             //  2.10 MB
    ushort_t* xqh    = (ushort_t*)alloc(8192L * 1024 * 2);   // 16.78 MB
    ushort_t* VTall  = (ushort_t*)alloc(1024L * 8192 * 2);   // 16.78 MB
    float*    scores = (float*)alloc(8L * NN * 4);           // 33.55 MB (ws)
    float* sigma     = (float*)alloc(8192 * 4);
    float* rowsum    = (float*)alloc(8192 * 4);
    ushort_t* Sh     = xh;    // S overlays xh (x dead after sc_vt)

    // 1. prep (x->bf16+sigma+rowsum | WvT) + G = Wk*Wq^T (pipelined)
    prep_g<<<256, 512, 0, stream>>>(x, Ws, Wq, Wk, Wv, xh, sigma, rowsum, WvT, G);
    // 2. xq = x * (Wq Wk^T)   (256 blocks, by-fastest XCD chunking)
    gemm3b<1><<<256, 512, 0, stream>>>(
        xh, G, xqh, 1024, 1024, 1024, 0, 0, 0, 1.f, 4, 64, 0);
    // 3. scores (128 @256^2, batch=XCD) | VT (128 @256^2, chunked)
    sc_vt<<<256, 512, 0, stream>>>(xqh, xh, scores, WvT, VTall);
    // 4. softmax over batch -> S (bf16) | prior P write (both HBM-bound)
    softmax_prior<<<5120, 256, 0, stream>>>(scores, Sh, sigma, rowsum, Pout);
    // 5. Z = S V  (full-chip 256-block gemm3b, one batch per XCD)
    gemm3b<0><<<256, 512, 0, stream>>>(
        Sh, VTall, Zout, 1024, 8192, 1024, NN, 1024, ND, 1.f, 8, 4, 1);
}

// Round 12
// 118.851 us; speedup vs baseline: 1.3332x; 1.0504x over previous
//
#include <hip/hip_runtime.h>
#include <hip/hip_fp16.h>

// AnomalyAttention forward, MI355X gfx950.
// B=8, N=1024, D=1024. Out = [Z (8*1024*1024 f32), P (8*1024*1024 f32)].
// Round 12: round-11 (124.8 us) + fp16 scores (halves sc_vt write traffic
// and softmax fetch; numerically safe: scores ~O(10) << 65504, 0.05% rel).
// Graph: prep_g / xq(gemm3b) / sc_vt(g256 pair, fp16 scores) /
//        softmax_prior(fp16 in) / sv(gemm3b)

typedef __attribute__((ext_vector_type(8))) short bf16x8;
typedef __attribute__((ext_vector_type(4))) float f32x4;
typedef unsigned short ushort_t;

#define DI __device__ __forceinline__

constexpr long NN = 1024L * 1024L;
constexpr long ND = 1024L * 1024L;

DI ushort_t f2bf(float f) {  // round-to-nearest-even f32 -> bf16 bits
    unsigned int u = __float_as_uint(f);
    u = u + 0x7fffu + ((u >> 16) & 1u);
    return (ushort_t)(u >> 16);
}
DI ushort_t f2h(float f) {   // f32 -> fp16 bits (RNE)
    __half h = __float2half(f);
    return *(ushort_t*)&h;
}
DI float h2f(ushort_t u) {
    __half h = *(__half*)&u;
    return __half2float(h);
}

// ---------------------------------------------------------------------------
// 128x256 pipelined GEMM body (verified round-3/6/9): 3 LDS buffers, XOR
// swizzle, 2 phases/K-tile, prefetch distance 2, vmcnt(6). UNCHANGED.
// ---------------------------------------------------------------------------
template <int OUT_BF16>
DI void g3b_body(const ushort_t* __restrict__ Ab, const ushort_t* __restrict__ Bb,
                 void* __restrict__ Cb, int ldA, int ldB, int ldC,
                 float scale, int bx, int by, ushort_t* lds)
{
    constexpr int BUF   = 24576;
    constexpr int B_OFF = 8192;

    const int tid  = threadIdx.x;
    const int wave = tid >> 6;
    const int lane = tid & 63;
    const int wm   = wave >> 2;
    const int wn   = wave & 3;
    const int gm   = bx * 128;
    const int gn   = by * 256;

    const int srow = tid >> 3;
    const int scol = 8 * ((tid & 7) ^ (srow & 7));
    const int sdst = wave * 512;

    auto stageA = [&](int t, int d, int h) {
        const ushort_t* src = Ab + (long)(gm + h * 64 + srow) * ldA + t * 64 + scol;
        __builtin_amdgcn_global_load_lds(
            (const __attribute__((address_space(1))) void*)src,
            (__attribute__((address_space(3))) void*)(&lds[d * BUF + h * 4096 + sdst]),
            16, 0, 0);
    };
    auto stageB = [&](int t, int d, int h, int j) {
        const ushort_t* src = Bb + (long)(gn + h * 128 + j * 64 + srow) * ldB + t * 64 + scol;
        __builtin_amdgcn_global_load_lds(
            (const __attribute__((address_space(1))) void*)src,
            (__attribute__((address_space(3))) void*)(&lds[d * BUF + B_OFF + h * 8192 + j * 4096 + sdst]),
            16, 0, 0);
    };

    const int arow = wm * 64 + (lane & 15);
    const int brow = wn * 64 + (lane & 15);
    const int cs0 = (((lane >> 4) * 16) ^ ((lane & 7) << 4)) >> 1;
    const int cs1 = ((64 + (lane >> 4) * 16) ^ ((lane & 7) << 4)) >> 1;

    f32x4 acc[4][4];
#pragma unroll
    for (int m = 0; m < 4; ++m)
#pragma unroll
        for (int n = 0; n < 4; ++n) acc[m][n] = (f32x4){0.f, 0.f, 0.f, 0.f};

    stageA(0, 0, 0); stageA(0, 0, 1);
    stageB(0, 0, 0, 0); stageB(0, 0, 0, 1); stageB(0, 0, 1, 0); stageB(0, 0, 1, 1);
    stageA(1, 1, 0); stageA(1, 1, 1);
    stageB(1, 1, 0, 0); stageB(1, 1, 0, 1); stageB(1, 1, 1, 0); stageB(1, 1, 1, 1);
    asm volatile("s_waitcnt vmcnt(6)" ::: "memory");
    __builtin_amdgcn_s_barrier();
    __builtin_amdgcn_sched_barrier(0);

    int cur = 0;
    for (int t = 0; t < 16; ++t) {
        const int nxt = (cur == 0) ? 2 : cur - 1;
        const ushort_t* la = &lds[cur * BUF];
        const ushort_t* lb = &lds[cur * BUF + B_OFF];

        bf16x8 a[2][4], b[2][4];
#pragma unroll
        for (int mi = 0; mi < 4; ++mi) {
            a[0][mi] = *(const bf16x8*)&la[(arow + mi * 16) * 64 + cs0];
            a[1][mi] = *(const bf16x8*)&la[(arow + mi * 16) * 64 + cs1];
        }
#pragma unroll
        for (int ni = 0; ni < 2; ++ni) {
            b[0][ni] = *(const bf16x8*)&lb[(brow + ni * 16) * 64 + cs0];
            b[1][ni] = *(const bf16x8*)&lb[(brow + ni * 16) * 64 + cs1];
        }
        if (t < 14) {
            stageB(t + 2, nxt, 0, 0); stageB(t + 2, nxt, 0, 1);
            stageB(t + 2, nxt, 1, 0); stageB(t + 2, nxt, 1, 1);
        }
        __builtin_amdgcn_s_barrier();
        asm volatile("s_waitcnt lgkmcnt(0)" ::: "memory");
        __builtin_amdgcn_sched_barrier(0);
        __builtin_amdgcn_s_setprio(1);
#pragma unroll
        for (int mi = 0; mi < 4; ++mi)
#pragma unroll
            for (int ni = 0; ni < 2; ++ni) {
                acc[mi][ni] = __builtin_amdgcn_mfma_f32_16x16x32_bf16(a[0][mi], b[0][ni], acc[mi][ni], 0, 0, 0);
                acc[mi][ni] = __builtin_amdgcn_mfma_f32_16x16x32_bf16(a[1][mi], b[1][ni], acc[mi][ni], 0, 0, 0);
            }
        __builtin_amdgcn_s_setprio(0);
        __builtin_amdgcn_s_barrier();
        __builtin_amdgcn_sched_barrier(0);

#pragma unroll
        for (int ni = 2; ni < 4; ++ni) {
            b[0][ni] = *(const bf16x8*)&lb[(brow + ni * 16) * 64 + cs0];
            b[1][ni] = *(const bf16x8*)&lb[(brow + ni * 16) * 64 + cs1];
        }
        if (t < 14) { stageA(t + 2, nxt, 0); stageA(t + 2, nxt, 1); }
        __builtin_amdgcn_s_barrier();
        asm volatile("s_waitcnt lgkmcnt(0)" ::: "memory");
        if (t < 14) asm volatile("s_waitcnt vmcnt(6)" ::: "memory");
        else        asm volatile("s_waitcnt vmcnt(0)" ::: "memory");
        __builtin_amdgcn_sched_barrier(0);
        __builtin_amdgcn_s_setprio(1);
#pragma unroll
        for (int mi = 0; mi < 4; ++mi)
#pragma unroll
            for (int ni = 2; ni < 4; ++ni) {
                acc[mi][ni] = __builtin_amdgcn_mfma_f32_16x16x32_bf16(a[0][mi], b[0][ni], acc[mi][ni], 0, 0, 0);
                acc[mi][ni] = __builtin_amdgcn_mfma_f32_16x16x32_bf16(a[1][mi], b[1][ni], acc[mi][ni], 0, 0, 0);
            }
        __builtin_amdgcn_s_setprio(0);
        __builtin_amdgcn_s_barrier();
        __builtin_amdgcn_sched_barrier(0);

        cur = (cur == 2) ? 0 : cur + 1;
    }

    if (OUT_BF16) {
        ushort_t* el = lds;
#pragma unroll
        for (int mi = 0; mi < 4; ++mi)
#pragma unroll
            for (int ni = 0; ni < 4; ++ni)
#pragma unroll
                for (int r = 0; r < 4; ++r)
                    el[(wm * 64 + mi * 16 + (lane >> 4) * 4 + r) * 256 +
                       wn * 64 + ni * 16 + (lane & 15)] = f2bf(acc[mi][ni][r] * scale);
        __builtin_amdgcn_s_barrier();
        ushort_t* C = (ushort_t*)Cb;
#pragma unroll
        for (int rr = 0; rr < 8; ++rr) {
            const int row = rr * 16 + (tid >> 5);
            const int col = (tid & 31) * 8;
            *(bf16x8*)&C[(long)(gm + row) * ldC + gn + col] =
                *(const bf16x8*)&el[row * 256 + col];
        }
    } else {
        float* el = (float*)lds;
        float* C  = (float*)Cb;
#pragma unroll
        for (int h = 0; h < 2; ++h) {
            if (wm == h) {
#pragma unroll
                for (int mi = 0; mi < 4; ++mi)
#pragma unroll
                    for (int ni = 0; ni < 4; ++ni)
#pragma unroll
                        for (int r = 0; r < 4; ++r)
                            el[(mi * 16 + (lane >> 4) * 4 + r) * 256 +
                               wn * 64 + ni * 16 + (lane & 15)] = acc[mi][ni][r] * scale;
            }
            __builtin_amdgcn_s_barrier();
#pragma unroll
            for (int i = 0; i < 8; ++i) {
                const int cc  = i * 512 + tid;
                const int row = cc >> 6;
                const int c4  = (cc & 63) * 4;
                *(float4*)&C[(long)(gm + h * 64 + row) * ldC + gn + c4] =
                    *(const float4*)&el[row * 256 + c4];
            }
            __builtin_amdgcn_s_barrier();
        }
    }
}

template <int OUT_BF16>
__global__ __launch_bounds__(512, 2)
void gemm3b(const ushort_t* __restrict__ A, const ushort_t* __restrict__ B,
            void* __restrict__ Cout, int ldA, int ldB, int ldC,
            long sA, long sB, long sC, float scale,
            int n0, int n1, int xfirst)
{
    __shared__ ushort_t lds[3 * 24576];
    const int total = gridDim.x;
    const int lin   = blockIdx.x;
    const int swz   = (lin & 7) * (total >> 3) + (lin >> 3);
    const int c0    = swz % n0;
    const int rem   = swz / n0;
    const int c1    = rem % n1;
    const int bz    = rem / n1;
    const int bx    = xfirst ? c0 : c1;
    const int by    = xfirst ? c1 : c0;
    void* Cb = OUT_BF16 ? (void*)((ushort_t*)Cout + (long)bz * sC)
                        : (void*)((float*)Cout + (long)bz * sC);
    g3b_body<OUT_BF16>(A + (long)bz * sA, B + (long)bz * sB, Cb,
                       ldA, ldB, ldC, scale, bx, by, lds);
}

// ---------------------------------------------------------------------------
// 256x256 8-phase GEMM body (verified round-4/9): BK=64, 8 waves 2Mx4N,
// per-wave 128x64, 2 LDS bufs, counted vmcnt(8). Sync structure UNCHANGED.
// OUT_MODE: 0 = f32 out, 1 = bf16 out, 2 = fp16 out.
// ---------------------------------------------------------------------------
template <int OUT_MODE>
DI void g256_body(const ushort_t* __restrict__ Ab, const ushort_t* __restrict__ Bb,
                  void* __restrict__ Cb, int ldA, int ldB, int ldC,
                  float scale, int bx, int by, ushort_t* ldsp)
{
    constexpr int BUF   = 32768;
    constexpr int B_OFF = 16384;

    const int tid  = threadIdx.x;
    const int wave = tid >> 6;
    const int lane = tid & 63;
    const int wm   = wave >> 2;
    const int wn   = wave & 3;
    const int gm   = bx * 256;
    const int gn   = by * 256;

    const int srow = tid >> 3;
    const int scol = 8 * ((tid & 7) ^ (srow & 7));
    const int sdst = wave * 512;

    auto stage = [&](int t, int d, int op, int h) {
        const ushort_t* g  = op ? Bb : Ab;
        const int       ld = op ? ldB : ldA;
        const int       g0 = (op ? gn : gm) + h * 128;
#pragma unroll
        for (int j = 0; j < 2; ++j) {
            const ushort_t* src = g + (long)(g0 + j * 64 + srow) * ld + t * 64 + scol;
            __builtin_amdgcn_global_load_lds(
                (const __attribute__((address_space(1))) void*)src,
                (__attribute__((address_space(3))) void*)
                    (&ldsp[d * BUF + op * B_OFF + h * 8192 + j * 4096 + sdst]),
                16, 0, 0);
        }
    };

    const int arow = wm * 128 + (lane & 15);
    const int brow = wn * 64 + (lane & 15);
    const int cs0 = (((lane >> 4) * 16) ^ ((lane & 7) << 4)) >> 1;
    const int cs1 = ((64 + (lane >> 4) * 16) ^ ((lane & 7) << 4)) >> 1;

    f32x4 acc[8][4];
#pragma unroll
    for (int m = 0; m < 8; ++m)
#pragma unroll
        for (int n = 0; n < 4; ++n) acc[m][n] = (f32x4){0.f, 0.f, 0.f, 0.f};

    stage(0, 0, 0, 0); stage(0, 0, 0, 1); stage(0, 0, 1, 0); stage(0, 0, 1, 1);
    stage(1, 1, 0, 0); stage(1, 1, 0, 1); stage(1, 1, 1, 0); stage(1, 1, 1, 1);
    asm volatile("s_waitcnt vmcnt(8)" ::: "memory");
    __builtin_amdgcn_s_barrier();
    __builtin_amdgcn_sched_barrier(0);

    bf16x8 a[2][4], b0[2][2], b1[2][2];
#pragma unroll 2
    for (int t = 0; t < 16; ++t) {
        const int cur = t & 1;
        const ushort_t* la = &ldsp[cur * BUF];
        const ushort_t* lb = &ldsp[cur * BUF + B_OFF];

        // ph1
#pragma unroll
        for (int mi = 0; mi < 4; ++mi) {
            a[0][mi] = *(const bf16x8*)&la[(arow + mi * 16) * 64 + cs0];
            a[1][mi] = *(const bf16x8*)&la[(arow + mi * 16) * 64 + cs1];
        }
#pragma unroll
        for (int ni = 0; ni < 2; ++ni) {
            b0[0][ni] = *(const bf16x8*)&lb[(brow + ni * 16) * 64 + cs0];
            b0[1][ni] = *(const bf16x8*)&lb[(brow + ni * 16) * 64 + cs1];
        }
        __builtin_amdgcn_s_barrier();
        asm volatile("s_waitcnt lgkmcnt(0)" ::: "memory");
        __builtin_amdgcn_sched_barrier(0);
        __builtin_amdgcn_s_setprio(1);
#pragma unroll
        for (int mi = 0; mi < 4; ++mi)
#pragma unroll
            for (int ni = 0; ni < 2; ++ni) {
                acc[mi][ni] = __builtin_amdgcn_mfma_f32_16x16x32_bf16(a[0][mi], b0[0][ni], acc[mi][ni], 0, 0, 0);
                acc[mi][ni] = __builtin_amdgcn_mfma_f32_16x16x32_bf16(a[1][mi], b0[1][ni], acc[mi][ni], 0, 0, 0);
            }
        __builtin_amdgcn_s_setprio(0);
        __builtin_amdgcn_s_barrier();
        __builtin_amdgcn_sched_barrier(0);

        // ph2
#pragma unroll
        for (int ni = 0; ni < 2; ++ni) {
            b1[0][ni] = *(const bf16x8*)&lb[(brow + (ni + 2) * 16) * 64 + cs0];
            b1[1][ni] = *(const bf16x8*)&lb[(brow + (ni + 2) * 16) * 64 + cs1];
        }
        __builtin_amdgcn_s_barrier();
        asm volatile("s_waitcnt lgkmcnt(0)" ::: "memory");
        __builtin_amdgcn_sched_barrier(0);
        __builtin_amdgcn_s_setprio(1);
#pragma unroll
        for (int mi = 0; mi < 4; ++mi)
#pragma unroll
            for (int ni = 0; ni < 2; ++ni) {
                acc[mi][ni + 2] = __builtin_amdgcn_mfma_f32_16x16x32_bf16(a[0][mi], b1[0][ni], acc[mi][ni + 2], 0, 0, 0);
                acc[mi][ni + 2] = __builtin_amdgcn_mfma_f32_16x16x32_bf16(a[1][mi], b1[1][ni], acc[mi][ni + 2], 0, 0, 0);
            }
        __builtin_amdgcn_s_setprio(0);
        __builtin_amdgcn_s_barrier();
        __builtin_amdgcn_sched_barrier(0);

        // ph3
#pragma unroll
        for (int mi = 0; mi < 4; ++mi) {
            a[0][mi] = *(const bf16x8*)&la[(arow + (mi + 4) * 16) * 64 + cs0];
            a[1][mi] = *(const bf16x8*)&la[(arow + (mi + 4) * 16) * 64 + cs1];
        }
        if (t < 14) { stage(t + 2, cur, 1, 0); stage(t + 2, cur, 1, 1); }
        __builtin_amdgcn_s_barrier();
        asm volatile("s_waitcnt lgkmcnt(0)" ::: "memory");
        __builtin_amdgcn_sched_barrier(0);
        __builtin_amdgcn_s_setprio(1);
#pragma unroll
        for (int mi = 0; mi < 4; ++mi)
#pragma unroll
            for (int ni = 0; ni < 2; ++ni) {
                acc[mi + 4][ni + 2] = __builtin_amdgcn_mfma_f32_16x16x32_bf16(a[0][mi], b1[0][ni], acc[mi + 4][ni + 2], 0, 0, 0);
                acc[mi + 4][ni + 2] = __builtin_amdgcn_mfma_f32_16x16x32_bf16(a[1][mi], b1[1][ni], acc[mi + 4][ni + 2], 0, 0, 0);
            }
        __builtin_amdgcn_s_setprio(0);
        __builtin_amdgcn_s_barrier();
        __builtin_amdgcn_sched_barrier(0);

        // ph4
        if (t < 14) { stage(t + 2, cur, 0, 0); stage(t + 2, cur, 0, 1); }
        if (t < 14)       asm volatile("s_waitcnt vmcnt(8)" ::: "memory");
        else if (t == 14) asm volatile("s_waitcnt vmcnt(0)" ::: "memory");
        __builtin_amdgcn_sched_barrier(0);
        __builtin_amdgcn_s_setprio(1);
#pragma unroll
        for (int mi = 0; mi < 4; ++mi)
#pragma unroll
            for (int ni = 0; ni < 2; ++ni) {
                acc[mi + 4][ni] = __builtin_amdgcn_mfma_f32_16x16x32_bf16(a[0][mi], b0[0][ni], acc[mi + 4][ni], 0, 0, 0);
                acc[mi + 4][ni] = __builtin_amdgcn_mfma_f32_16x16x32_bf16(a[1][mi], b0[1][ni], acc[mi + 4][ni], 0, 0, 0);
            }
        __builtin_amdgcn_s_setprio(0);
        __builtin_amdgcn_s_barrier();
        __builtin_amdgcn_sched_barrier(0);
    }

    if (OUT_MODE != 0) {
        // 16-bit output (bf16 or fp16), LDS-staged for coalesced 16B stores
        ushort_t* el = ldsp;
#pragma unroll
        for (int mi = 0; mi < 8; ++mi)
#pragma unroll
            for (int ni = 0; ni < 4; ++ni)
#pragma unroll
                for (int r = 0; r < 4; ++r) {
                    const float v = acc[mi][ni][r] * scale;
                    el[(wm * 128 + mi * 16 + (lane >> 4) * 4 + r) * 256 +
                       wn * 64 + ni * 16 + (lane & 15)] =
                        (OUT_MODE == 1) ? f2bf(v) : f2h(v);
                }
        __builtin_amdgcn_s_barrier();
        ushort_t* C = (ushort_t*)Cb;
#pragma unroll
        for (int i = 0; i < 16; ++i) {
            const int cc  = i * 512 + tid;
            const int row = cc >> 5;
            const int col = (cc & 31) * 8;
            *(bf16x8*)&C[(long)(gm + row) * ldC + gn + col] =
                *(const bf16x8*)&el[row * 256 + col];
        }
    } else {
        float* el = (float*)ldsp;
        float* C  = (float*)Cb;
#pragma unroll
        for (int h = 0; h < 2; ++h) {
            if (wm == h) {
#pragma unroll
                for (int mi = 0; mi < 8; ++mi)
#pragma unroll
                    for (int ni = 0; ni < 4; ++ni)
#pragma unroll
                        for (int r = 0; r < 4; ++r)
                            el[(mi * 16 + (lane >> 4) * 4 + r) * 256 +
                               wn * 64 + ni * 16 + (lane & 15)] = acc[mi][ni][r] * scale;
            }
            __builtin_amdgcn_s_barrier();
#pragma unroll
            for (int i = 0; i < 16; ++i) {
                const int cc  = i * 512 + tid;
                const int row = cc >> 6;
                const int c4  = (cc & 63) * 4;
                *(float4*)&C[(long)(gm + h * 128 + row) * ldC + gn + c4] =
                    *(const float4*)&el[row * 256 + c4];
            }
            __builtin_amdgcn_s_barrier();
        }
    }
}

// ---------------------------------------------------------------------------
// prep_g: 256 blocks x 512 thr (1 block/CU), ~20.5 KB LDS. UNCHANGED (r9).
// ---------------------------------------------------------------------------
__global__ __launch_bounds__(512)
void prep_g(const float* __restrict__ x, const float* __restrict__ Ws,
            const float* __restrict__ Wq, const float* __restrict__ Wk,
            const float* __restrict__ Wv,
            ushort_t* __restrict__ xh, float* __restrict__ sigma,
            float* __restrict__ rowsum,
            ushort_t* __restrict__ WvT, ushort_t* __restrict__ G)
{
    __shared__ char smem[20608];
    const int blk = blockIdx.x;
    const int tid = threadIdx.x;

    if (blk < 160) {
        const int wave = tid >> 6, lane = tid & 63;
        for (int row = blk * 8 + wave; row < 8192; row += 1280) {
            const float* xr = x + (long)row * 1024;
            float dot = 0.f;
#pragma unroll
            for (int c = 0; c < 4; ++c) {
                const int i = c * 256 + lane * 4;
                float4 v = *(const float4*)(xr + i);
                float4 w = *(const float4*)(Ws + i);
                dot += v.x * w.x + v.y * w.y + v.z * w.z + v.w * w.w;
                ushort4 o;
                o.x = f2bf(v.x); o.y = f2bf(v.y); o.z = f2bf(v.z); o.w = f2bf(v.w);
                *(ushort4*)(xh + (long)row * 1024 + i) = o;
            }
#pragma unroll
            for (int o = 32; o; o >>= 1) dot += __shfl_down(dot, o);
            float sg;
            if (lane == 0) {
                float s = 1.f / (1.f + __expf(-5.f * dot)) + 1e-5f;
                sg = exp2f(s * 1.5849625007211562f) - 1.f;   // 3^s - 1
            }
            sg = __shfl(sg, 0);
            const int i = row & 1023;
            const float c = -0.5f / (sg * sg);
            float a = 0.f;
            for (int j = lane; j < 1024; j += 64) {
                float d = (float)(i - j);
                a += __expf(c * d * d);
            }
#pragma unroll
            for (int o = 32; o; o >>= 1) a += __shfl_down(a, o);
            if (lane == 0) {
                sigma[row]  = sg;
                rowsum[row] = (0.3989422804014327f / sg) * a;
            }
        }
    } else if (blk < 192) {
        float (*s)[65] = (float(*)[65])smem;
        const int r = tid >> 4, c4 = (tid & 15) * 4;
#pragma unroll
        for (int it = 0; it < 8; ++it) {
            const int tile = (blk - 160) * 8 + it;
            const int tr = (tile >> 4) * 64, tc = (tile & 15) * 64;
#pragma unroll
            for (int rr = r; rr < 64; rr += 32) {
                float4 v = *(const float4*)(Wv + (long)(tr + rr) * 1024 + tc + c4);
                s[rr][c4] = v.x; s[rr][c4 + 1] = v.y; s[rr][c4 + 2] = v.z; s[rr][c4 + 3] = v.w;
            }
            __syncthreads();
#pragma unroll
            for (int rr = r; rr < 64; rr += 32) {
                ushort4 o;
                o.x = f2bf(s[c4][rr]);     o.y = f2bf(s[c4 + 1][rr]);
                o.z = f2bf(s[c4 + 2][rr]); o.w = f2bf(s[c4 + 3][rr]);
                *(ushort4*)(WvT + (long)(tc + rr) * 1024 + tr + c4) = o;
            }
            __syncthreads();
        }
    } else {
        ushort_t* sA = (ushort_t*)smem;
        ushort_t* sB = sA + 5120;
        const int g  = blk - 192;
        const int gm = (g >> 3) * 128, gn = (g & 7) * 128;
        const int wave = tid >> 6, lane = tid & 63;
        const int wm = wave >> 2, wn = wave & 3;
        const int lrow = tid >> 3, lcol = (tid & 7) * 4;
        const float* A0 = Wk + (long)(gm + lrow) * 1024 + lcol;
        const float* A1 = Wk + (long)(gm + 64 + lrow) * 1024 + lcol;
        const float* B0 = Wq + (long)(gn + lrow) * 1024 + lcol;
        const float* B1 = Wq + (long)(gn + 64 + lrow) * 1024 + lcol;

        f32x4 acc[4][2];
#pragma unroll
        for (int m = 0; m < 4; ++m)
#pragma unroll
            for (int n = 0; n < 2; ++n) acc[m][n] = (f32x4){0.f, 0.f, 0.f, 0.f};

        auto wr = [&](float4 a0, float4 a1, float4 b0, float4 b1) {
            ushort4 o;
            o.x = f2bf(a0.x); o.y = f2bf(a0.y); o.z = f2bf(a0.z); o.w = f2bf(a0.w);
            *(ushort4*)&sA[lrow * 40 + lcol] = o;
            o.x = f2bf(a1.x); o.y = f2bf(a1.y); o.z = f2bf(a1.z); o.w = f2bf(a1.w);
            *(ushort4*)&sA[(64 + lrow) * 40 + lcol] = o;
            o.x = f2bf(b0.x); o.y = f2bf(b0.y); o.z = f2bf(b0.z); o.w = f2bf(b0.w);
            *(ushort4*)&sB[lrow * 40 + lcol] = o;
            o.x = f2bf(b1.x); o.y = f2bf(b1.y); o.z = f2bf(b1.z); o.w = f2bf(b1.w);
            *(ushort4*)&sB[(64 + lrow) * 40 + lcol] = o;
        };
        auto mm = [&]() {
            bf16x8 af[4], bfv[2];
#pragma unroll
            for (int mi = 0; mi < 4; ++mi)
                af[mi] = *(const bf16x8*)&sA[(wm * 64 + mi * 16 + (lane & 15)) * 40 + (lane >> 4) * 8];
#pragma unroll
            for (int ni = 0; ni < 2; ++ni)
                bfv[ni] = *(const bf16x8*)&sB[(wn * 32 + ni * 16 + (lane & 15)) * 40 + (lane >> 4) * 8];
#pragma unroll
            for (int mi = 0; mi < 4; ++mi)
#pragma unroll
                for (int ni = 0; ni < 2; ++ni)
                    acc[mi][ni] = __builtin_amdgcn_mfma_f32_16x16x32_bf16(af[mi], bfv[ni], acc[mi][ni], 0, 0, 0);
        };

        float4 a0A = *(const float4*)(A0);      float4 a1A = *(const float4*)(A1);
        float4 b0A = *(const float4*)(B0);      float4 b1A = *(const float4*)(B1);
        float4 a0B = *(const float4*)(A0 + 32); float4 a1B = *(const float4*)(A1 + 32);
        float4 b0B = *(const float4*)(B0 + 32); float4 b1B = *(const float4*)(B1 + 32);

        for (int k0 = 0; k0 < 1024; k0 += 64) {
            wr(a0A, a1A, b0A, b1A);
            if (k0 < 960) {
                a0A = *(const float4*)(A0 + k0 + 64); a1A = *(const float4*)(A1 + k0 + 64);
                b0A = *(const float4*)(B0 + k0 + 64); b1A = *(const float4*)(B1 + k0 + 64);
            }
            __syncthreads();
            mm();
            __syncthreads();
            wr(a0B, a1B, b0B, b1B);
            if (k0 < 928) {
                a0B = *(const float4*)(A0 + k0 + 96); a1B = *(const float4*)(A1 + k0 + 96);
                b0B = *(const float4*)(B0 + k0 + 96); b1B = *(const float4*)(B1 + k0 + 96);
            }
            __syncthreads();
            mm();
            __syncthreads();
        }
#pragma unroll
        for (int mi = 0; mi < 4; ++mi)
#pragma unroll
            for (int ni = 0; ni < 2; ++ni)
#pragma unroll
                for (int r = 0; r < 4; ++r)
                    G[(long)(gm + wm * 64 + mi * 16 + (lane >> 4) * 4 + r) * 1024 +
                      gn + wn * 32 + ni * 16 + (lane & 15)] = f2bf(acc[mi][ni][r]);
    }
}

// ---------------------------------------------------------------------------
// sc_vt: 256 blocks x 512 thr, 128 KB LDS (one residency round).
//   lin 0..127:   scores_b = xq_b * x_b^T / 32 (fp16 out -> ws), b = lin&7
//   lin 128..255: VT = Wv^T x^T (bf16, ld 8192)
// ---------------------------------------------------------------------------
__global__ __launch_bounds__(512, 2)
void sc_vt(const ushort_t* __restrict__ xqh, const ushort_t* __restrict__ xh,
           ushort_t* __restrict__ scoresH,
           const ushort_t* __restrict__ WvT, ushort_t* __restrict__ VTall)
{
    __shared__ ushort_t lds[2 * 32768];
    const int lin = blockIdx.x;
    if (lin < 128) {
        const int bz = lin & 7;
        const int t  = lin >> 3;
        g256_body<2>(xqh + (long)bz * ND, xh + (long)bz * ND,
                     (void*)(scoresH + (long)bz * NN),
                     1024, 1024, 1024, 0.03125f, t & 3, t >> 2, lds);
    } else {
        const int l  = lin - 128;
        const int l2 = (l & 7) * 16 + (l >> 3);
        g256_body<1>(WvT, xh, (void*)VTall,
                     1024, 1024, 8192, 1.f, l2 & 3, l2 >> 2, lds);
    }
}

// ---------------------------------------------------------------------------
// softmax_prior: 5120 blocks x 256 thr, memory-bound.
//   blocks 0..4095:    batch softmax over fp16 scores -> S (bf16)
//   blocks 4096..5119: prior P -> Pout (each block derives batchsum; 8 rows)
// ---------------------------------------------------------------------------
__global__ __launch_bounds__(256)
void softmax_prior(const ushort_t* __restrict__ scoresH, ushort_t* __restrict__ S,
                   const float* __restrict__ sigma, const float* __restrict__ rowsum,
                   float* __restrict__ P)
{
    __shared__ float sred[256];
    const int blk = blockIdx.x;
    const int tid = threadIdx.x;
    if (blk < 4096) {
        const long idx = (long)blk * 256 + tid;
        float v[8], m = -1e30f;
#pragma unroll
        for (int b = 0; b < 8; ++b) { v[b] = h2f(scoresH[(long)b * NN + idx]); m = fmaxf(m, v[b]); }
        float sum = 0.f;
#pragma unroll
        for (int b = 0; b < 8; ++b) { v[b] = __expf(v[b] - m); sum += v[b]; }
        const float inv = 1.f / sum;
#pragma unroll
        for (int b = 0; b < 8; ++b) S[(long)b * NN + idx] = f2bf(v[b] * inv);
    } else {
        const int l = blk - 4096;          // 0..1023
        const int b = l >> 7;              // 128 blocks per batch
        float a = rowsum[b * 1024 + tid]       + rowsum[b * 1024 + 256 + tid] +
                  rowsum[b * 1024 + 512 + tid] + rowsum[b * 1024 + 768 + tid];
        sred[tid] = a; __syncthreads();
        for (int o = 128; o; o >>= 1) { if (tid < o) sred[tid] += sred[tid + o]; __syncthreads(); }
        const float bs = sred[0];
        const int r0 = (l & 127) * 8;      // 8 rows per block
#pragma unroll
        for (int it = 0; it < 8; ++it) {
            const int e   = it * 256 + tid;
            const int row = r0 + (e >> 8);
            const int j4  = (e & 255) * 4;
            const float sg  = sigma[(b << 10) + row];
            const float c   = -0.5f / (sg * sg);
            const float inv = 0.3989422804014327f / (sg * bs);
            float4 o;
            float d;
            d = (float)(row - j4);       o.x = inv * __expf(c * d * d);
            d = (float)(row - j4 - 1);   o.y = inv * __expf(c * d * d);
            d = (float)(row - j4 - 2);   o.z = inv * __expf(c * d * d);
            d = (float)(row - j4 - 3);   o.w = inv * __expf(c * d * d);
            *(float4*)&P[(long)b * NN + (long)row * 1024 + j4] = o;
        }
    }
}

// ---------------------------------------------------------------------------
extern "C" void kernel_launch(void* const* d_in, const int* in_sizes, int n_in,
                              void* d_out, int out_size, void* d_ws, size_t ws_size,
                              hipStream_t stream)
{
    const float* x  = (const float*)d_in[0];
    const float* Wq = (const float*)d_in[1];
    const float* Wk = (const float*)d_in[2];
    const float* Wv = (const float*)d_in[3];
    const float* Ws = (const float*)d_in[4];
    float* Zout = (float*)d_out;
    float* Pout = Zout + 8 * ND;

    char* base = (char*)d_ws;
    size_t off = 0;
    auto alloc = [&](size_t bytes) {
        void* p = base + off;
        off = (off + bytes + 255) & ~(size_t)255;
        return p;
    };
    ushort_t* xh      = (ushort_t*)alloc(8192L * 1024 * 2);   // 16.78 MB
    ushort_t* G       = (ushort_t*)alloc(NN * 2);             //  2.10 MB
    ushort_t* WvT     = (ushort_t*)alloc(NN * 2);             //  2.10 MB
    ushort_t* xqh     = (ushort_t*)alloc(8192L * 1024 * 2);   // 16.78 MB
    ushort_t* VTall   = (ushort_t*)alloc(1024L * 8192 * 2);   // 16.78 MB
    ushort_t* scoresH = (ushort_t*)alloc(8L * NN * 2);        // 16.78 MB (fp16)
    float* sigma      = (float*)alloc(8192 * 4);
    float* rowsum     = (float*)alloc(8192 * 4);
    ushort_t* Sh      = xh;    // S overlays xh (x dead after sc_vt)

    // 1. prep (x->bf16+sigma+rowsum | WvT) + G = Wk*Wq^T (pipelined)
    prep_g<<<256, 512, 0, stream>>>(x, Ws, Wq, Wk, Wv, xh, sigma, rowsum, WvT, G);
    // 2. xq = x * (Wq Wk^T)   (256 blocks, by-fastest XCD chunking)
    gemm3b<1><<<256, 512, 0, stream>>>(
        xh, G, xqh, 1024, 1024, 1024, 0, 0, 0, 1.f, 4, 64, 0);
    // 3. scores fp16 (128 @256^2, batch=XCD) | VT (128 @256^2, chunked)
    sc_vt<<<256, 512, 0, stream>>>(xqh, xh, scoresH, WvT, VTall);
    // 4. softmax over batch (fp16 in) -> S (bf16) | prior P write
    softmax_prior<<<5120, 256, 0, stream>>>(scoresH, Sh, sigma, rowsum, Pout);
    // 5. Z = S V  (full-chip 256-block gemm3b, one batch per XCD)
    gemm3b<0><<<256, 512, 0, stream>>>(
        Sh, VTall, Zout, 1024, 8192, 1024, NN, 1024, ND, 1.f, 8, 4, 1);
}

// Round 14
// 117.874 us; speedup vs baseline: 1.3442x; 1.0083x over previous
//
#include <hip/hip_runtime.h>
#include <hip/hip_fp16.h>

// AnomalyAttention forward, MI355X gfx950.
// B=8, N=1024, D=1024. Out = [Z (8*1024*1024 f32), P (8*1024*1024 f32)].
// Round 14: round-13 with the g2b bf16-epilogue store-loop FIXED
// (was writing only cols 0..63 of each row: i<2, cc>>3, (cc&7)*8;
//  now full tile: 2048 chunks, i<4, row=cc>>4, col=(cc&15)*8).
// g2b: 128x128 tile, BK=64, 2 LDS bufs = 64 KB -> 2 blocks/CU (xq, sv).

typedef __attribute__((ext_vector_type(8))) short bf16x8;
typedef __attribute__((ext_vector_type(4))) float f32x4;
typedef unsigned short ushort_t;

#define DI __device__ __forceinline__

constexpr long NN = 1024L * 1024L;
constexpr long ND = 1024L * 1024L;

DI ushort_t f2bf(float f) {  // round-to-nearest-even f32 -> bf16 bits
    unsigned int u = __float_as_uint(f);
    u = u + 0x7fffu + ((u >> 16) & 1u);
    return (ushort_t)(u >> 16);
}
DI ushort_t f2h(float f) {   // f32 -> fp16 bits (RNE)
    __half h = __float2half(f);
    return *(ushort_t*)&h;
}
DI float h2f(ushort_t u) {
    __half h = *(__half*)&u;
    return __half2float(h);
}

// ---------------------------------------------------------------------------
// g2b: 128x128 tile, BK=64, 8 waves (2M x 4N, per-wave 64x32 = acc[4][2]),
// 2 LDS buffers (64 KB) -> 2 blocks/CU. Ledger:
//  prologue: stage t0->buf0 (4), t1->buf1 (4); vmcnt(4) [t0 landed]; bar.
//  tile t (cur=t&1):
//   ph1: 12 ds_reads; bar#1; lgkm0 (reads drained); MFMA mi0-1
//   ph2: bar#2 (all waves drained buf cur) -> stage t+2 -> buf cur (4);
//        vmcnt(4): drains t+1's 4 loads (issued tile t-1); MFMA mi2-3;
//        bar#3 publishes t+1.
//  Tail: t==14 stages nothing, vmcnt(0) drains t15.
// ---------------------------------------------------------------------------
template <int OUT_BF16>
DI void g2b_body(const ushort_t* __restrict__ Ab, const ushort_t* __restrict__ Bb,
                 void* __restrict__ Cb, int ldA, int ldB, int ldC,
                 float scale, int bx, int by, ushort_t* lds)
{
    constexpr int BUF   = 16384;   // ushorts per buf: A 8192 + B 8192
    constexpr int B_OFF = 8192;

    const int tid  = threadIdx.x;
    const int wave = tid >> 6;
    const int lane = tid & 63;
    const int wm   = wave >> 2;   // 0..1
    const int wn   = wave & 3;    // 0..3
    const int gm   = bx * 128;
    const int gn   = by * 128;

    const int srow = tid >> 3;
    const int scol = 8 * ((tid & 7) ^ (srow & 7));
    const int sdst = wave * 512;

    auto stage = [&](int t, int d, int op, int h) {   // op 0=A 1=B, h half
        const ushort_t* g  = op ? Bb : Ab;
        const int       ld = op ? ldB : ldA;
        const int       g0 = (op ? gn : gm) + h * 64;
        const ushort_t* src = g + (long)(g0 + srow) * ld + t * 64 + scol;
        __builtin_amdgcn_global_load_lds(
            (const __attribute__((address_space(1))) void*)src,
            (__attribute__((address_space(3))) void*)
                (&lds[d * BUF + op * B_OFF + h * 4096 + sdst]),
            16, 0, 0);
    };

    const int arow = wm * 64 + (lane & 15);
    const int brow = wn * 32 + (lane & 15);
    const int cs0 = (((lane >> 4) * 16) ^ ((lane & 7) << 4)) >> 1;
    const int cs1 = ((64 + (lane >> 4) * 16) ^ ((lane & 7) << 4)) >> 1;

    f32x4 acc[4][2];
#pragma unroll
    for (int m = 0; m < 4; ++m)
#pragma unroll
        for (int n = 0; n < 2; ++n) acc[m][n] = (f32x4){0.f, 0.f, 0.f, 0.f};

    // prologue
    stage(0, 0, 0, 0); stage(0, 0, 0, 1); stage(0, 0, 1, 0); stage(0, 0, 1, 1);
    stage(1, 1, 0, 0); stage(1, 1, 0, 1); stage(1, 1, 1, 0); stage(1, 1, 1, 1);
    asm volatile("s_waitcnt vmcnt(4)" ::: "memory");   // tile0 resident
    __builtin_amdgcn_s_barrier();
    __builtin_amdgcn_sched_barrier(0);

#pragma unroll 2
    for (int t = 0; t < 16; ++t) {
        const int cur = t & 1;
        const ushort_t* la = &lds[cur * BUF];
        const ushort_t* lb = &lds[cur * BUF + B_OFF];

        bf16x8 a[2][4], b[2][2];
        // ---- ph1: all reads; MFMA mi 0..1 ----
#pragma unroll
        for (int mi = 0; mi < 4; ++mi) {
            a[0][mi] = *(const bf16x8*)&la[(arow + mi * 16) * 64 + cs0];
            a[1][mi] = *(const bf16x8*)&la[(arow + mi * 16) * 64 + cs1];
        }
#pragma unroll
        for (int ni = 0; ni < 2; ++ni) {
            b[0][ni] = *(const bf16x8*)&lb[(brow + ni * 16) * 64 + cs0];
            b[1][ni] = *(const bf16x8*)&lb[(brow + ni * 16) * 64 + cs1];
        }
        __builtin_amdgcn_s_barrier();                          // bar#1
        asm volatile("s_waitcnt lgkmcnt(0)" ::: "memory");
        __builtin_amdgcn_sched_barrier(0);
        __builtin_amdgcn_s_setprio(1);
#pragma unroll
        for (int mi = 0; mi < 2; ++mi)
#pragma unroll
            for (int ni = 0; ni < 2; ++ni) {
                acc[mi][ni] = __builtin_amdgcn_mfma_f32_16x16x32_bf16(a[0][mi], b[0][ni], acc[mi][ni], 0, 0, 0);
                acc[mi][ni] = __builtin_amdgcn_mfma_f32_16x16x32_bf16(a[1][mi], b[1][ni], acc[mi][ni], 0, 0, 0);
            }
        __builtin_amdgcn_s_setprio(0);
        __builtin_amdgcn_sched_barrier(0);
        __builtin_amdgcn_s_barrier();                          // bar#2
        __builtin_amdgcn_sched_barrier(0);

        // ---- ph2: stage t+2 -> buf cur (reads drained by all waves) ----
        if (t < 14) {
            stage(t + 2, cur, 0, 0); stage(t + 2, cur, 0, 1);
            stage(t + 2, cur, 1, 0); stage(t + 2, cur, 1, 1);
        }
        if (t < 14)       asm volatile("s_waitcnt vmcnt(4)" ::: "memory");
        else if (t == 14) asm volatile("s_waitcnt vmcnt(0)" ::: "memory");
        __builtin_amdgcn_sched_barrier(0);
        __builtin_amdgcn_s_setprio(1);
#pragma unroll
        for (int mi = 2; mi < 4; ++mi)
#pragma unroll
            for (int ni = 0; ni < 2; ++ni) {
                acc[mi][ni] = __builtin_amdgcn_mfma_f32_16x16x32_bf16(a[0][mi], b[0][ni], acc[mi][ni], 0, 0, 0);
                acc[mi][ni] = __builtin_amdgcn_mfma_f32_16x16x32_bf16(a[1][mi], b[1][ni], acc[mi][ni], 0, 0, 0);
            }
        __builtin_amdgcn_s_setprio(0);
        __builtin_amdgcn_sched_barrier(0);
        __builtin_amdgcn_s_barrier();                          // bar#3: publish
        __builtin_amdgcn_sched_barrier(0);
    }

    // epilogue. C/D layout: col = lane&15, row = (lane>>4)*4 + r
    if (OUT_BF16) {
        ushort_t* el = lds;   // [128][128] ushort = 32 KB
#pragma unroll
        for (int mi = 0; mi < 4; ++mi)
#pragma unroll
            for (int ni = 0; ni < 2; ++ni)
#pragma unroll
                for (int r = 0; r < 4; ++r)
                    el[(wm * 64 + mi * 16 + (lane >> 4) * 4 + r) * 128 +
                       wn * 32 + ni * 16 + (lane & 15)] = f2bf(acc[mi][ni][r] * scale);
        __builtin_amdgcn_s_barrier();
        ushort_t* C = (ushort_t*)Cb;
#pragma unroll
        for (int i = 0; i < 4; ++i) {
            const int cc  = i * 512 + tid;      // 2048 x 16B chunks (FIXED)
            const int row = cc >> 4;            // 16 chunks per 128-col row
            const int col = (cc & 15) * 8;
            *(bf16x8*)&C[(long)(gm + row) * ldC + gn + col] =
                *(const bf16x8*)&el[row * 128 + col];
        }
    } else {
        float* el = (float*)lds;   // [128][128] f32 = 64 KB (both bufs)
        float* C  = (float*)Cb;
#pragma unroll
        for (int mi = 0; mi < 4; ++mi)
#pragma unroll
            for (int ni = 0; ni < 2; ++ni)
#pragma unroll
                for (int r = 0; r < 4; ++r)
                    el[(wm * 64 + mi * 16 + (lane >> 4) * 4 + r) * 128 +
                       wn * 32 + ni * 16 + (lane & 15)] = acc[mi][ni][r] * scale;
        __builtin_amdgcn_s_barrier();
#pragma unroll
        for (int i = 0; i < 8; ++i) {
            const int cc  = i * 512 + tid;      // 4096 x 16B chunks
            const int row = cc >> 5;
            const int c4  = (cc & 31) * 4;
            *(float4*)&C[(long)(gm + row) * ldC + gn + c4] =
                *(const float4*)&el[row * 128 + c4];
        }
    }
}

template <int OUT_BF16>
__global__ __launch_bounds__(512, 4)
void g2b(const ushort_t* __restrict__ A, const ushort_t* __restrict__ B,
         void* __restrict__ Cout, int ldA, int ldB, int ldC,
         long sA, long sB, long sC, float scale,
         int n0, int n1, int xfirst)
{
    __shared__ ushort_t lds[2 * 16384];   // 64 KB -> 2 blocks/CU
    const int total = gridDim.x;
    const int lin   = blockIdx.x;
    const int swz   = (lin & 7) * (total >> 3) + (lin >> 3);
    const int c0    = swz % n0;
    const int rem   = swz / n0;
    const int c1    = rem % n1;
    const int bz    = rem / n1;
    const int bx    = xfirst ? c0 : c1;
    const int by    = xfirst ? c1 : c0;
    void* Cb = OUT_BF16 ? (void*)((ushort_t*)Cout + (long)bz * sC)
                        : (void*)((float*)Cout + (long)bz * sC);
    g2b_body<OUT_BF16>(A + (long)bz * sA, B + (long)bz * sB, Cb,
                       ldA, ldB, ldC, scale, bx, by, lds);
}

// ---------------------------------------------------------------------------
// 256x256 8-phase GEMM body (verified round-4/9): BK=64, 8 waves 2Mx4N,
// per-wave 128x64, 2 LDS bufs, counted vmcnt(8). UNCHANGED.
// OUT_MODE: 0 = f32 out, 1 = bf16 out, 2 = fp16 out.
// ---------------------------------------------------------------------------
template <int OUT_MODE>
DI void g256_body(const ushort_t* __restrict__ Ab, const ushort_t* __restrict__ Bb,
                  void* __restrict__ Cb, int ldA, int ldB, int ldC,
                  float scale, int bx, int by, ushort_t* ldsp)
{
    constexpr int BUF   = 32768;
    constexpr int B_OFF = 16384;

    const int tid  = threadIdx.x;
    const int wave = tid >> 6;
    const int lane = tid & 63;
    const int wm   = wave >> 2;
    const int wn   = wave & 3;
    const int gm   = bx * 256;
    const int gn   = by * 256;

    const int srow = tid >> 3;
    const int scol = 8 * ((tid & 7) ^ (srow & 7));
    const int sdst = wave * 512;

    auto stage = [&](int t, int d, int op, int h) {
        const ushort_t* g  = op ? Bb : Ab;
        const int       ld = op ? ldB : ldA;
        const int       g0 = (op ? gn : gm) + h * 128;
#pragma unroll
        for (int j = 0; j < 2; ++j) {
            const ushort_t* src = g + (long)(g0 + j * 64 + srow) * ld + t * 64 + scol;
            __builtin_amdgcn_global_load_lds(
                (const __attribute__((address_space(1))) void*)src,
                (__attribute__((address_space(3))) void*)
                    (&ldsp[d * BUF + op * B_OFF + h * 8192 + j * 4096 + sdst]),
                16, 0, 0);
        }
    };

    const int arow = wm * 128 + (lane & 15);
    const int brow = wn * 64 + (lane & 15);
    const int cs0 = (((lane >> 4) * 16) ^ ((lane & 7) << 4)) >> 1;
    const int cs1 = ((64 + (lane >> 4) * 16) ^ ((lane & 7) << 4)) >> 1;

    f32x4 acc[8][4];
#pragma unroll
    for (int m = 0; m < 8; ++m)
#pragma unroll
        for (int n = 0; n < 4; ++n) acc[m][n] = (f32x4){0.f, 0.f, 0.f, 0.f};

    stage(0, 0, 0, 0); stage(0, 0, 0, 1); stage(0, 0, 1, 0); stage(0, 0, 1, 1);
    stage(1, 1, 0, 0); stage(1, 1, 0, 1); stage(1, 1, 1, 0); stage(1, 1, 1, 1);
    asm volatile("s_waitcnt vmcnt(8)" ::: "memory");
    __builtin_amdgcn_s_barrier();
    __builtin_amdgcn_sched_barrier(0);

    bf16x8 a[2][4], b0[2][2], b1[2][2];
#pragma unroll 2
    for (int t = 0; t < 16; ++t) {
        const int cur = t & 1;
        const ushort_t* la = &ldsp[cur * BUF];
        const ushort_t* lb = &ldsp[cur * BUF + B_OFF];

        // ph1
#pragma unroll
        for (int mi = 0; mi < 4; ++mi) {
            a[0][mi] = *(const bf16x8*)&la[(arow + mi * 16) * 64 + cs0];
            a[1][mi] = *(const bf16x8*)&la[(arow + mi * 16) * 64 + cs1];
        }
#pragma unroll
        for (int ni = 0; ni < 2; ++ni) {
            b0[0][ni] = *(const bf16x8*)&lb[(brow + ni * 16) * 64 + cs0];
            b0[1][ni] = *(const bf16x8*)&lb[(brow + ni * 16) * 64 + cs1];
        }
        __builtin_amdgcn_s_barrier();
        asm volatile("s_waitcnt lgkmcnt(0)" ::: "memory");
        __builtin_amdgcn_sched_barrier(0);
        __builtin_amdgcn_s_setprio(1);
#pragma unroll
        for (int mi = 0; mi < 4; ++mi)
#pragma unroll
            for (int ni = 0; ni < 2; ++ni) {
                acc[mi][ni] = __builtin_amdgcn_mfma_f32_16x16x32_bf16(a[0][mi], b0[0][ni], acc[mi][ni], 0, 0, 0);
                acc[mi][ni] = __builtin_amdgcn_mfma_f32_16x16x32_bf16(a[1][mi], b0[1][ni], acc[mi][ni], 0, 0, 0);
            }
        __builtin_amdgcn_s_setprio(0);
        __builtin_amdgcn_s_barrier();
        __builtin_amdgcn_sched_barrier(0);

        // ph2
#pragma unroll
        for (int ni = 0; ni < 2; ++ni) {
            b1[0][ni] = *(const bf16x8*)&lb[(brow + (ni + 2) * 16) * 64 + cs0];
            b1[1][ni] = *(const bf16x8*)&lb[(brow + (ni + 2) * 16) * 64 + cs1];
        }
        __builtin_amdgcn_s_barrier();
        asm volatile("s_waitcnt lgkmcnt(0)" ::: "memory");
        __builtin_amdgcn_sched_barrier(0);
        __builtin_amdgcn_s_setprio(1);
#pragma unroll
        for (int mi = 0; mi < 4; ++mi)
#pragma unroll
            for (int ni = 0; ni < 2; ++ni) {
                acc[mi][ni + 2] = __builtin_amdgcn_mfma_f32_16x16x32_bf16(a[0][mi], b1[0][ni], acc[mi][ni + 2], 0, 0, 0);
                acc[mi][ni + 2] = __builtin_amdgcn_mfma_f32_16x16x32_bf16(a[1][mi], b1[1][ni], acc[mi][ni + 2], 0, 0, 0);
            }
        __builtin_amdgcn_s_setprio(0);
        __builtin_amdgcn_s_barrier();
        __builtin_amdgcn_sched_barrier(0);

        // ph3
#pragma unroll
        for (int mi = 0; mi < 4; ++mi) {
            a[0][mi] = *(const bf16x8*)&la[(arow + (mi + 4) * 16) * 64 + cs0];
            a[1][mi] = *(const bf16x8*)&la[(arow + (mi + 4) * 16) * 64 + cs1];
        }
        if (t < 14) { stage(t + 2, cur, 1, 0); stage(t + 2, cur, 1, 1); }
        __builtin_amdgcn_s_barrier();
        asm volatile("s_waitcnt lgkmcnt(0)" ::: "memory");
        __builtin_amdgcn_sched_barrier(0);
        __builtin_amdgcn_s_setprio(1);
#pragma unroll
        for (int mi = 0; mi < 4; ++mi)
#pragma unroll
            for (int ni = 0; ni < 2; ++ni) {
                acc[mi + 4][ni + 2] = __builtin_amdgcn_mfma_f32_16x16x32_bf16(a[0][mi], b1[0][ni], acc[mi + 4][ni + 2], 0, 0, 0);
                acc[mi + 4][ni + 2] = __builtin_amdgcn_mfma_f32_16x16x32_bf16(a[1][mi], b1[1][ni], acc[mi + 4][ni + 2], 0, 0, 0);
            }
        __builtin_amdgcn_s_setprio(0);
        __builtin_amdgcn_s_barrier();
        __builtin_amdgcn_sched_barrier(0);

        // ph4
        if (t < 14) { stage(t + 2, cur, 0, 0); stage(t + 2, cur, 0, 1); }
        if (t < 14)       asm volatile("s_waitcnt vmcnt(8)" ::: "memory");
        else if (t == 14) asm volatile("s_waitcnt vmcnt(0)" ::: "memory");
        __builtin_amdgcn_sched_barrier(0);
        __builtin_amdgcn_s_setprio(1);
#pragma unroll
        for (int mi = 0; mi < 4; ++mi)
#pragma unroll
            for (int ni = 0; ni < 2; ++ni) {
                acc[mi + 4][ni] = __builtin_amdgcn_mfma_f32_16x16x32_bf16(a[0][mi], b0[0][ni], acc[mi + 4][ni], 0, 0, 0);
                acc[mi + 4][ni] = __builtin_amdgcn_mfma_f32_16x16x32_bf16(a[1][mi], b0[1][ni], acc[mi + 4][ni], 0, 0, 0);
            }
        __builtin_amdgcn_s_setprio(0);
        __builtin_amdgcn_s_barrier();
        __builtin_amdgcn_sched_barrier(0);
    }

    if (OUT_MODE != 0) {
        ushort_t* el = ldsp;
#pragma unroll
        for (int mi = 0; mi < 8; ++mi)
#pragma unroll
            for (int ni = 0; ni < 4; ++ni)
#pragma unroll
                for (int r = 0; r < 4; ++r) {
                    const float v = acc[mi][ni][r] * scale;
                    el[(wm * 128 + mi * 16 + (lane >> 4) * 4 + r) * 256 +
                       wn * 64 + ni * 16 + (lane & 15)] =
                        (OUT_MODE == 1) ? f2bf(v) : f2h(v);
                }
        __builtin_amdgcn_s_barrier();
        ushort_t* C = (ushort_t*)Cb;
#pragma unroll
        for (int i = 0; i < 16; ++i) {
            const int cc  = i * 512 + tid;
            const int row = cc >> 5;
            const int col = (cc & 31) * 8;
            *(bf16x8*)&C[(long)(gm + row) * ldC + gn + col] =
                *(const bf16x8*)&el[row * 256 + col];
        }
    } else {
        float* el = (float*)ldsp;
        float* C  = (float*)Cb;
#pragma unroll
        for (int h = 0; h < 2; ++h) {
            if (wm == h) {
#pragma unroll
                for (int mi = 0; mi < 8; ++mi)
#pragma unroll
                    for (int ni = 0; ni < 4; ++ni)
#pragma unroll
                        for (int r = 0; r < 4; ++r)
                            el[(mi * 16 + (lane >> 4) * 4 + r) * 256 +
                               wn * 64 + ni * 16 + (lane & 15)] = acc[mi][ni][r] * scale;
            }
            __builtin_amdgcn_s_barrier();
#pragma unroll
            for (int i = 0; i < 16; ++i) {
                const int cc  = i * 512 + tid;
                const int row = cc >> 6;
                const int c4  = (cc & 63) * 4;
                *(float4*)&C[(long)(gm + h * 128 + row) * ldC + gn + c4] =
                    *(const float4*)&el[row * 256 + c4];
            }
            __builtin_amdgcn_s_barrier();
        }
    }
}

// ---------------------------------------------------------------------------
// prep_g: 256 blocks x 512 thr (1 block/CU), ~20.5 KB LDS. UNCHANGED (r9).
// ---------------------------------------------------------------------------
__global__ __launch_bounds__(512)
void prep_g(const float* __restrict__ x, const float* __restrict__ Ws,
            const float* __restrict__ Wq, const float* __restrict__ Wk,
            const float* __restrict__ Wv,
            ushort_t* __restrict__ xh, float* __restrict__ sigma,
            float* __restrict__ rowsum,
            ushort_t* __restrict__ WvT, ushort_t* __restrict__ G)
{
    __shared__ char smem[20608];
    const int blk = blockIdx.x;
    const int tid = threadIdx.x;

    if (blk < 160) {
        const int wave = tid >> 6, lane = tid & 63;
        for (int row = blk * 8 + wave; row < 8192; row += 1280) {
            const float* xr = x + (long)row * 1024;
            float dot = 0.f;
#pragma unroll
            for (int c = 0; c < 4; ++c) {
                const int i = c * 256 + lane * 4;
                float4 v = *(const float4*)(xr + i);
                float4 w = *(const float4*)(Ws + i);
                dot += v.x * w.x + v.y * w.y + v.z * w.z + v.w * w.w;
                ushort4 o;
                o.x = f2bf(v.x); o.y = f2bf(v.y); o.z = f2bf(v.z); o.w = f2bf(v.w);
                *(ushort4*)(xh + (long)row * 1024 + i) = o;
            }
#pragma unroll
            for (int o = 32; o; o >>= 1) dot += __shfl_down(dot, o);
            float sg;
            if (lane == 0) {
                float s = 1.f / (1.f + __expf(-5.f * dot)) + 1e-5f;
                sg = exp2f(s * 1.5849625007211562f) - 1.f;   // 3^s - 1
            }
            sg = __shfl(sg, 0);
            const int i = row & 1023;
            const float c = -0.5f / (sg * sg);
            float a = 0.f;
            for (int j = lane; j < 1024; j += 64) {
                float d = (float)(i - j);
                a += __expf(c * d * d);
            }
#pragma unroll
            for (int o = 32; o; o >>= 1) a += __shfl_down(a, o);
            if (lane == 0) {
                sigma[row]  = sg;
                rowsum[row] = (0.3989422804014327f / sg) * a;
            }
        }
    } else if (blk < 192) {
        float (*s)[65] = (float(*)[65])smem;
        const int r = tid >> 4, c4 = (tid & 15) * 4;
#pragma unroll
        for (int it = 0; it < 8; ++it) {
            const int tile = (blk - 160) * 8 + it;
            const int tr = (tile >> 4) * 64, tc = (tile & 15) * 64;
#pragma unroll
            for (int rr = r; rr < 64; rr += 32) {
                float4 v = *(const float4*)(Wv + (long)(tr + rr) * 1024 + tc + c4);
                s[rr][c4] = v.x; s[rr][c4 + 1] = v.y; s[rr][c4 + 2] = v.z; s[rr][c4 + 3] = v.w;
            }
            __syncthreads();
#pragma unroll
            for (int rr = r; rr < 64; rr += 32) {
                ushort4 o;
                o.x = f2bf(s[c4][rr]);     o.y = f2bf(s[c4 + 1][rr]);
                o.z = f2bf(s[c4 + 2][rr]); o.w = f2bf(s[c4 + 3][rr]);
                *(ushort4*)(WvT + (long)(tc + rr) * 1024 + tr + c4) = o;
            }
            __syncthreads();
        }
    } else {
        ushort_t* sA = (ushort_t*)smem;
        ushort_t* sB = sA + 5120;
        const int g  = blk - 192;
        const int gm = (g >> 3) * 128, gn = (g & 7) * 128;
        const int wave = tid >> 6, lane = tid & 63;
        const int wm = wave >> 2, wn = wave & 3;
        const int lrow = tid >> 3, lcol = (tid & 7) * 4;
        const float* A0 = Wk + (long)(gm + lrow) * 1024 + lcol;
        const float* A1 = Wk + (long)(gm + 64 + lrow) * 1024 + lcol;
        const float* B0 = Wq + (long)(gn + lrow) * 1024 + lcol;
        const float* B1 = Wq + (long)(gn + 64 + lrow) * 1024 + lcol;

        f32x4 acc[4][2];
#pragma unroll
        for (int m = 0; m < 4; ++m)
#pragma unroll
            for (int n = 0; n < 2; ++n) acc[m][n] = (f32x4){0.f, 0.f, 0.f, 0.f};

        auto wr = [&](float4 a0, float4 a1, float4 b0, float4 b1) {
            ushort4 o;
            o.x = f2bf(a0.x); o.y = f2bf(a0.y); o.z = f2bf(a0.z); o.w = f2bf(a0.w);
            *(ushort4*)&sA[lrow * 40 + lcol] = o;
            o.x = f2bf(a1.x); o.y = f2bf(a1.y); o.z = f2bf(a1.z); o.w = f2bf(a1.w);
            *(ushort4*)&sA[(64 + lrow) * 40 + lcol] = o;
            o.x = f2bf(b0.x); o.y = f2bf(b0.y); o.z = f2bf(b0.z); o.w = f2bf(b0.w);
            *(ushort4*)&sB[lrow * 40 + lcol] = o;
            o.x = f2bf(b1.x); o.y = f2bf(b1.y); o.z = f2bf(b1.z); o.w = f2bf(b1.w);
            *(ushort4*)&sB[(64 + lrow) * 40 + lcol] = o;
        };
        auto mm = [&]() {
            bf16x8 af[4], bfv[2];
#pragma unroll
            for (int mi = 0; mi < 4; ++mi)
                af[mi] = *(const bf16x8*)&sA[(wm * 64 + mi * 16 + (lane & 15)) * 40 + (lane >> 4) * 8];
#pragma unroll
            for (int ni = 0; ni < 2; ++ni)
                bfv[ni] = *(const bf16x8*)&sB[(wn * 32 + ni * 16 + (lane & 15)) * 40 + (lane >> 4) * 8];
#pragma unroll
            for (int mi = 0; mi < 4; ++mi)
#pragma unroll
                for (int ni = 0; ni < 2; ++ni)
                    acc[mi][ni] = __builtin_amdgcn_mfma_f32_16x16x32_bf16(af[mi], bfv[ni], acc[mi][ni], 0, 0, 0);
        };

        float4 a0A = *(const float4*)(A0);      float4 a1A = *(const float4*)(A1);
        float4 b0A = *(const float4*)(B0);      float4 b1A = *(const float4*)(B1);
        float4 a0B = *(const float4*)(A0 + 32); float4 a1B = *(const float4*)(A1 + 32);
        float4 b0B = *(const float4*)(B0 + 32); float4 b1B = *(const float4*)(B1 + 32);

        for (int k0 = 0; k0 < 1024; k0 += 64) {
            wr(a0A, a1A, b0A, b1A);
            if (k0 < 960) {
                a0A = *(const float4*)(A0 + k0 + 64); a1A = *(const float4*)(A1 + k0 + 64);
                b0A = *(const float4*)(B0 + k0 + 64); b1A = *(const float4*)(B1 + k0 + 64);
            }
            __syncthreads();
            mm();
            __syncthreads();
            wr(a0B, a1B, b0B, b1B);
            if (k0 < 928) {
                a0B = *(const float4*)(A0 + k0 + 96); a1B = *(const float4*)(A1 + k0 + 96);
                b0B = *(const float4*)(B0 + k0 + 96); b1B = *(const float4*)(B1 + k0 + 96);
            }
            __syncthreads();
            mm();
            __syncthreads();
        }
#pragma unroll
        for (int mi = 0; mi < 4; ++mi)
#pragma unroll
            for (int ni = 0; ni < 2; ++ni)
#pragma unroll
                for (int r = 0; r < 4; ++r)
                    G[(long)(gm + wm * 64 + mi * 16 + (lane >> 4) * 4 + r) * 1024 +
                      gn + wn * 32 + ni * 16 + (lane & 15)] = f2bf(acc[mi][ni][r]);
    }
}

// ---------------------------------------------------------------------------
// sc_vt: 256 blocks x 512 thr, 128 KB LDS (one residency round). UNCHANGED.
// ---------------------------------------------------------------------------
__global__ __launch_bounds__(512, 2)
void sc_vt(const ushort_t* __restrict__ xqh, const ushort_t* __restrict__ xh,
           ushort_t* __restrict__ scoresH,
           const ushort_t* __restrict__ WvT, ushort_t* __restrict__ VTall)
{
    __shared__ ushort_t lds[2 * 32768];
    const int lin = blockIdx.x;
    if (lin < 128) {
        const int bz = lin & 7;
        const int t  = lin >> 3;
        g256_body<2>(xqh + (long)bz * ND, xh + (long)bz * ND,
                     (void*)(scoresH + (long)bz * NN),
                     1024, 1024, 1024, 0.03125f, t & 3, t >> 2, lds);
    } else {
        const int l  = lin - 128;
        const int l2 = (l & 7) * 16 + (l >> 3);
        g256_body<1>(WvT, xh, (void*)VTall,
                     1024, 1024, 8192, 1.f, l2 & 3, l2 >> 2, lds);
    }
}

// ---------------------------------------------------------------------------
// softmax_prior: 5120 blocks x 256 thr, memory-bound. UNCHANGED.
// ---------------------------------------------------------------------------
__global__ __launch_bounds__(256)
void softmax_prior(const ushort_t* __restrict__ scoresH, ushort_t* __restrict__ S,
                   const float* __restrict__ sigma, const float* __restrict__ rowsum,
                   float* __restrict__ P)
{
    __shared__ float sred[256];
    const int blk = blockIdx.x;
    const int tid = threadIdx.x;
    if (blk < 4096) {
        const long idx = (long)blk * 256 + tid;
        float v[8], m = -1e30f;
#pragma unroll
        for (int b = 0; b < 8; ++b) { v[b] = h2f(scoresH[(long)b * NN + idx]); m = fmaxf(m, v[b]); }
        float sum = 0.f;
#pragma unroll
        for (int b = 0; b < 8; ++b) { v[b] = __expf(v[b] - m); sum += v[b]; }
        const float inv = 1.f / sum;
#pragma unroll
        for (int b = 0; b < 8; ++b) S[(long)b * NN + idx] = f2bf(v[b] * inv);
    } else {
        const int l = blk - 4096;          // 0..1023
        const int b = l >> 7;              // 128 blocks per batch
        float a = rowsum[b * 1024 + tid]       + rowsum[b * 1024 + 256 + tid] +
                  rowsum[b * 1024 + 512 + tid] + rowsum[b * 1024 + 768 + tid];
        sred[tid] = a; __syncthreads();
        for (int o = 128; o; o >>= 1) { if (tid < o) sred[tid] += sred[tid + o]; __syncthreads(); }
        const float bs = sred[0];
        const int r0 = (l & 127) * 8;      // 8 rows per block
#pragma unroll
        for (int it = 0; it < 8; ++it) {
            const int e   = it * 256 + tid;
            const int row = r0 + (e >> 8);
            const int j4  = (e & 255) * 4;
            const float sg  = sigma[(b << 10) + row];
            const float c   = -0.5f / (sg * sg);
            const float inv = 0.3989422804014327f / (sg * bs);
            float4 o;
            float d;
            d = (float)(row - j4);       o.x = inv * __expf(c * d * d);
            d = (float)(row - j4 - 1);   o.y = inv * __expf(c * d * d);
            d = (float)(row - j4 - 2);   o.z = inv * __expf(c * d * d);
            d = (float)(row - j4 - 3);   o.w = inv * __expf(c * d * d);
            *(float4*)&P[(long)b * NN + (long)row * 1024 + j4] = o;
        }
    }
}

// ---------------------------------------------------------------------------
extern "C" void kernel_launch(void* const* d_in, const int* in_sizes, int n_in,
                              void* d_out, int out_size, void* d_ws, size_t ws_size,
                              hipStream_t stream)
{
    const float* x  = (const float*)d_in[0];
    const float* Wq = (const float*)d_in[1];
    const float* Wk = (const float*)d_in[2];
    const float* Wv = (const float*)d_in[3];
    const float* Ws = (const float*)d_in[4];
    float* Zout = (float*)d_out;
    float* Pout = Zout + 8 * ND;

    char* base = (char*)d_ws;
    size_t off = 0;
    auto alloc = [&](size_t bytes) {
        void* p = base + off;
        off = (off + bytes + 255) & ~(size_t)255;
        return p;
    };
    ushort_t* xh      = (ushort_t*)alloc(8192L * 1024 * 2);   // 16.78 MB
    ushort_t* G       = (ushort_t*)alloc(NN * 2);             //  2.10 MB
    ushort_t* WvT     = (ushort_t*)alloc(NN * 2);             //  2.10 MB
    ushort_t* xqh     = (ushort_t*)alloc(8192L * 1024 * 2);   // 16.78 MB
    ushort_t* VTall   = (ushort_t*)alloc(1024L * 8192 * 2);   // 16.78 MB
    ushort_t* scoresH = (ushort_t*)alloc(8L * NN * 2);        // 16.78 MB (fp16)
    float* sigma      = (float*)alloc(8192 * 4);
    float* rowsum     = (float*)alloc(8192 * 4);
    ushort_t* Sh      = xh;    // S overlays xh (x dead after sc_vt)

    // 1. prep (x->bf16+sigma+rowsum | WvT) + G = Wk*Wq^T (pipelined)
    prep_g<<<256, 512, 0, stream>>>(x, Ws, Wq, Wk, Wv, xh, sigma, rowsum, WvT, G);
    // 2. xq = x * (Wq Wk^T)   (512 blocks g2b, 2/CU; XCD chunk: 8 A-panels + G)
    g2b<1><<<512, 512, 0, stream>>>(
        xh, G, xqh, 1024, 1024, 1024, 0, 0, 0, 1.f, 8, 64, 0);
    // 3. scores fp16 (128 @256^2, batch=XCD) | VT (128 @256^2, chunked)
    sc_vt<<<256, 512, 0, stream>>>(xqh, xh, scoresH, WvT, VTall);
    // 4. softmax over batch (fp16 in) -> S (bf16) | prior P write
    softmax_prior<<<5120, 256, 0, stream>>>(scoresH, Sh, sigma, rowsum, Pout);
    // 5. Z = S V  (512 blocks g2b, 2/CU; one batch per XCD)
    g2b<0><<<512, 512, 0, stream>>>(
        Sh, VTall, Zout, 1024, 8192, 1024, NN, 1024, ND, 1.f, 8, 8, 1);
}